// Round 2
// baseline (1534.989 us; speedup 1.0000x reference)
//
#include <hip/hip_runtime.h>

#define NPART 1024
#define NNB   512

// ---------------------------------------------------------------- prep
__global__ void prep_kernel(const float* __restrict__ p0_enc, const float* __restrict__ v0_enc,
                            const float* __restrict__ p0, const float* __restrict__ v0,
                            const float* __restrict__ a, const float* __restrict__ liftc,
                            const float* __restrict__ liftd,
                            float* __restrict__ featsC, float* __restrict__ Fbuf,
                            float* __restrict__ p1out)
{
    int p = blockIdx.x;          // b*N + i
    int t = threadIdx.x;         // 128 threads: c*8 + m
    int c = t >> 3, m = t & 7;
    float v0x = v0[p*2+0], v0y = v0[p*2+1];
    float ax  = a[p*2+0],  ay  = a[p*2+1];
    float p0x = p0[p*2+0], p0y = p0[p*2+1];
    float v1x = v0x + ax, v1y = v0y + ay;
    float p1x = p0x + 0.5f*(v0x + v1x), p1y = p0y + 0.5f*(v0y + v1y);
    float vx, vy;
    if (c == 0)      { vx = v1x; vy = v1y; }
    else if (c == 1) { vx = p1x; vy = p1y; }
    else if (c < 9)  { vx = v0_enc[(p*7 + (c-2))*2+0]; vy = v0_enc[(p*7 + (c-2))*2+1]; }
    else             { vx = p0_enc[(p*7 + (c-9))*2+0]; vy = p0_enc[(p*7 + (c-9))*2+1]; }
    float th = (float)m * 0.7853981633974483f;
    float cs = cosf(th), sn = sinf(th);
    float lc0 = liftc[0], lc1 = liftc[1];
    float ld0 = liftd[0], ld1 = liftd[1];
    // lift[...,c,m] = vx*basis_x[m] + vy*basis_y[m]
    featsC[p*128 + t]        = vx*(lc0*cs - lc1*sn) + vy*(lc0*sn + lc1*cs);
    Fbuf[p*6272 + 6144 + t]  = vx*(ld0*cs - ld1*sn) + vy*(ld0*sn + ld1*cs);  // layer-0 dense tail
    if (t == 0) { p1out[p*2+0] = p1x; p1out[p*2+1] = p1y; }
}

// ---------------------------------------------------------------- pair weights (sparse: 4 bins/pair)
__global__ void pairs_kernel(const float* __restrict__ p1, const float* __restrict__ mask,
                             float4* __restrict__ W4, unsigned int* __restrict__ G4)
{
    int p  = blockIdx.x;          // b*N + i
    int b  = p >> 9;
    int ii = p & 511;
    int tid = threadIdx.x;        // 256
    float pix = p1[p*2+0], piy = p1[p*2+1];
    float relx[2], rely[2], dd[2], ww[2];
#pragma unroll
    for (int q = 0; q < 2; ++q) {
        int j  = tid + q*256;
        int jr = b*NNB + j;
        float rx = p1[jr*2+0] - pix;
        float ry = p1[jr*2+1] - piy;
        float d  = sqrtf(rx*rx + ry*ry + 1e-12f) * (1.0f/40.0f);
        float t1 = fmaxf(1.0f - d*d, 0.0f);
        float w  = t1*t1*t1 * mask[jr];
        relx[q] = rx; rely[q] = ry; dd[q] = d; ww[q] = w;
    }
    __shared__ float red[256];
    __shared__ float denomS;
    red[tid] = ww[0] + ww[1];
    __syncthreads();
    for (int s = 128; s > 0; s >>= 1) {
        if (tid < s) red[tid] += red[tid+s];
        __syncthreads();
    }
    if (tid == 0) denomS = 1.0f / (red[0] + 1e-6f);
    __syncthreads();
    float dinv = denomS;
#pragma unroll
    for (int q = 0; q < 2; ++q) {
        int j  = tid + q*256;
        float wb = ww[q] * dinv;
        float d  = dd[q];
        float rc  = fminf(fmaxf(d*3.0f - 0.5f, 0.0f), 2.0f);
        float r0f = floorf(rc);
        float wr  = rc - r0f;
        int r0 = (int)r0f;
        int r1 = min(r0 + 1, 2);
        float rx = (j == ii) ? 1.0f : relx[q];
        float ry = (j == ii) ? 0.0f : rely[q];
        float ang = atan2f(ry, rx);
        if (ang < 0.0f) ang += 6.283185307179586f;
        float tc  = ang * 2.546479089470325f;   // *16/(2*pi)
        float t0f = floorf(tc);
        float wt  = tc - t0f;
        int t0  = ((int)t0f) & 15;              // handles tc==16 edge like ref's %16
        int t1i = (t0 + 1) & 15;
        int g0 = r0*16 + t0, g1 = r0*16 + t1i, g2 = r1*16 + t0, g3 = r1*16 + t1i;
        float4 wv;
        wv.x = wb * (1.0f-wr) * (1.0f-wt);
        wv.y = wb * (1.0f-wr) * wt;
        wv.z = wb * wr * (1.0f-wt);
        wv.w = wb * wr * wt;
        int idx = p*NNB + j;
        W4[idx] = wv;
        G4[idx] = (unsigned)g0 | ((unsigned)g1<<8) | ((unsigned)g2<<16) | ((unsigned)g3<<24);
    }
}

// ---------------------------------------------------------------- sparse aggregation: F[g][c*8+n] in LDS
template<int C8>
__global__ __launch_bounds__(64) void aggregate_kernel(const float* __restrict__ actsrc, int actStride,
                                                       const float4* __restrict__ W4,
                                                       const unsigned int* __restrict__ G4,
                                                       float* __restrict__ Fbuf, int Krow)
{
    __shared__ float Fs[48*C8];
    int p = blockIdx.x;
    int pbase = p & ~511;            // b*N
    int tid = threadIdx.x;
    for (int i = tid; i < 48*C8; i += 64) Fs[i] = 0.0f;
    __syncthreads();
    const float4* Wp = W4 + p*NNB;
    const unsigned int* Gp = G4 + p*NNB;
    float4 w = Wp[0];
    unsigned int g = Gp[0];
    for (int j = 0; j < NNB; ++j) {
        float4 wc = w; unsigned int gc = g;
        if (j + 1 < NNB) { w = Wp[j+1]; g = Gp[j+1]; }   // prefetch
        if (wc.x == 0.0f && wc.y == 0.0f && wc.z == 0.0f && wc.w == 0.0f) continue;
        const float* row = actsrc + (pbase + j) * actStride;
        int b0 = gc & 255, b1 = (gc>>8) & 255, b2 = (gc>>16) & 255, b3 = (gc>>24) & 255;
        if (C8 == 128) {
            float2 f = ((const float2*)row)[tid];
            float2* F2 = (float2*)Fs;
            float2 v;
            v = F2[b0*64+tid]; v.x += wc.x*f.x; v.y += wc.x*f.y; F2[b0*64+tid] = v;
            v = F2[b1*64+tid]; v.x += wc.y*f.x; v.y += wc.y*f.y; F2[b1*64+tid] = v;
            v = F2[b2*64+tid]; v.x += wc.z*f.x; v.y += wc.z*f.y; F2[b2*64+tid] = v;
            v = F2[b3*64+tid]; v.x += wc.w*f.x; v.y += wc.w*f.y; F2[b3*64+tid] = v;
        } else {
            float f = row[tid];
            Fs[b0*C8+tid] += wc.x*f;
            Fs[b1*C8+tid] += wc.y*f;
            Fs[b2*C8+tid] += wc.z*f;
            Fs[b3*C8+tid] += wc.w*f;
        }
    }
    __syncthreads();
    float* dst = Fbuf + (size_t)p * Krow;
    const float4* Fsv = (const float4*)Fs;
    float4* dv = (float4*)dst;
    for (int i = tid; i < 48*C8/4; i += 64) dv[i] = Fsv[i];
}

// ---------------------------------------------------------------- expand weights into B matrices
// mode 0: standard (conv rows + dense rows -> same (o,m) col)
// mode 1: layer 0 block-diagonal (cols 0-31 conv o'=0..3, cols 32-63 dense o'=0..3)
// mode 2: layer 4, cols (c_out*2+a) with proj bases folded in
__global__ void expand_kernel(const float* __restrict__ Wc, const float* __restrict__ Wd,
                              const float* __restrict__ pc4, const float* __restrict__ pd4,
                              float* __restrict__ Bm, int C, int O8, int total, int mode)
{
    int e = blockIdx.x*blockDim.x + threadIdx.x;
    if (e >= total) return;
    int col = e % O8;
    int k   = e / O8;
    int C8  = C*8;
    bool conv = (k < 48*C8);
    int cc, nn, rr = 0, tt = 0;
    if (conv) {
        int g = k / C8, rem = k - g*C8;
        cc = rem >> 3; nn = rem & 7; rr = g >> 4; tt = g & 15;
    } else {
        int rem = k - 48*C8;
        cc = rem >> 3; nn = rem & 7;
    }
    float val = 0.0f;
    if (mode == 0) {
        int o = col >> 3, m = col & 7;
        if (conv) val = Wc[(((o*C + cc)*8 + ((nn - m) & 7))*3 + rr)*16 + ((tt - 2*m) & 15)];
        else      val = Wd[(o*C + cc)*8 + ((m - nn) & 7)];
    } else if (mode == 1) {
        int o = col >> 3, m = col & 7;
        if (col < 32) { if (conv)  val = Wc[(((o*C + cc)*8 + ((nn - m)&7))*3 + rr)*16 + ((tt - 2*m)&15)]; }
        else          { if (!conv) val = Wd[((o-4)*C + cc)*8 + ((m - nn)&7)]; }
    } else {
        if (col < 6) {
            int co = col >> 1, aa = col & 1;
            float s0 = conv ? pc4[0] : pd4[0];
            float s1 = conv ? pc4[1] : pd4[1];
#pragma unroll
            for (int m = 0; m < 8; ++m) {
                float th = (float)m * 0.7853981633974483f;
                float csv = cosf(th), snv = sinf(th);
                float bas = (aa == 0) ? (s0*csv - s1*snv) : (s0*snv + s1*csv);
                float wv;
                if (conv) wv = Wc[(((co*C + cc)*8 + ((nn - m)&7))*3 + rr)*16 + ((tt - 2*m)&15)];
                else      wv = Wd[(co*C + cc)*8 + ((m - nn)&7)];
                val += wv * bas;
            }
        }
    }
    Bm[e] = val;
}

// ---------------------------------------------------------------- f32 GEMM: C[1024][O8] = A[1024][Kdim] * B[Kdim][O8]
template<int O8>
__global__ __launch_bounds__(256) void gemm16(const float* __restrict__ A, int Kdim,
                                              const float* __restrict__ Bm, float* __restrict__ Cout)
{
    constexpr int NU = (O8 + 31) / 32;
    __shared__ float As[8*68];        // 8 rows, stride 68 (pad, 16B-aligned rows)
    __shared__ float Bs[64*O8];
    int tid = threadIdx.x;
    int m0  = blockIdx.x * 8;
    int m   = tid & 7, nb = tid >> 3;  // nb in 0..31
    float acc[NU];
#pragma unroll
    for (int u = 0; u < NU; ++u) acc[u] = 0.0f;
    for (int k0 = 0; k0 < Kdim; k0 += 64) {
        if (tid < 128) {
            int r = tid >> 4, q = tid & 15;
            *(float4*)(As + r*68 + q*4) = *(const float4*)(A + (size_t)(m0 + r)*Kdim + k0 + q*4);
        }
        for (int idx = tid; idx < 64*O8/4; idx += 256) {
            int r = idx / (O8/4), cq = idx % (O8/4);
            *(float4*)(Bs + r*O8 + cq*4) = *(const float4*)(Bm + (size_t)(k0 + r)*O8 + cq*4);
        }
        __syncthreads();
#pragma unroll
        for (int kk = 0; kk < 64; ++kk) {
            float av = As[m*68 + kk];
#pragma unroll
            for (int u = 0; u < NU; ++u) {
                int colu = nb + 32*u;
                if (O8 >= 32 || colu < O8) acc[u] += av * Bs[kk*O8 + colu];
            }
        }
        __syncthreads();
    }
#pragma unroll
    for (int u = 0; u < NU; ++u) {
        int colu = nb + 32*u;
        if (O8 >= 32 || colu < O8) Cout[(size_t)(m0 + m)*O8 + colu] = acc[u];
    }
}

// ---------------------------------------------------------------- per-layer epilogue: residual + mag_act -> next tail
__global__ void epilogue_kernel(const float* __restrict__ OG, int O, int res,
                                float* __restrict__ outBuf, float* __restrict__ actDst, int actStride)
{
    int id = blockIdx.x*blockDim.x + threadIdx.x;
    if (id >= NPART*O) return;
    int p = id / O, c = id % O;
    int O8 = O*8;
    const float* src = OG + (size_t)p*O8 + c*8;
    float* ob = outBuf + (size_t)p*O8 + c*8;
    float x[8]; float mag = 1e-6f;
#pragma unroll
    for (int m = 0; m < 8; ++m) {
        float v = src[m];
        if (res) v += ob[m];
        x[m] = v; mag += v*v;
    }
#pragma unroll
    for (int m = 0; m < 8; ++m) ob[m] = x[m];
    float sc = fmaxf(mag - 0.2f, 0.0f) / mag;
    float* ad = actDst + (size_t)p*actStride + c*8;
#pragma unroll
    for (int m = 0; m < 8; ++m) ad[m] = x[m]*sc;
}

// ---------------------------------------------------------------- final outputs
__global__ void final_kernel(const float* __restrict__ OG, const float* __restrict__ p1,
                             const float* __restrict__ p0, float* __restrict__ out)
{
    int p = blockIdx.x*blockDim.x + threadIdx.x;
    if (p >= NPART) return;
    const float s = 0.0078125f;  // 1/128
    float c0 = OG[p*8+0]*s, c1 = OG[p*8+1]*s;
    float c2 = OG[p*8+2]*s, c3 = OG[p*8+3]*s;
    float c4 = OG[p*8+4]*s, c5 = OG[p*8+5]*s;
    float pcx = p1[p*2+0] + c0, pcy = p1[p*2+1] + c1;
    out[p*2+0] = pcx; out[p*2+1] = pcy;
    out[2048 + p*2+0] = pcx - p0[p*2+0];
    out[2048 + p*2+1] = pcy - p0[p*2+1];
    out[4096 + p*4+0] = c2; out[4096 + p*4+1] = c3;
    out[4096 + p*4+2] = c4; out[4096 + p*4+3] = c5;
}

// ---------------------------------------------------------------- launch
extern "C" void kernel_launch(void* const* d_in, const int* in_sizes, int n_in,
                              void* d_out, int out_size, void* d_ws, size_t ws_size,
                              hipStream_t stream)
{
    const float* p0_enc  = (const float*)d_in[0];
    const float* v0_enc  = (const float*)d_in[1];
    const float* p0      = (const float*)d_in[2];
    const float* v0      = (const float*)d_in[3];
    const float* a       = (const float*)d_in[4];
    const float* mask    = (const float*)d_in[5];
    const float* lift_c0 = (const float*)d_in[6];
    const float* Wc0     = (const float*)d_in[7];
    const float* lift_d0 = (const float*)d_in[8];
    const float* Wd0     = (const float*)d_in[9];
    const float* Wc1     = (const float*)d_in[10];
    const float* Wd1     = (const float*)d_in[11];
    const float* Wc2     = (const float*)d_in[12];
    const float* Wd2     = (const float*)d_in[13];
    const float* Wc3     = (const float*)d_in[14];
    const float* Wd3     = (const float*)d_in[15];
    const float* Wc4     = (const float*)d_in[16];
    const float* pc4     = (const float*)d_in[17];
    const float* Wd4     = (const float*)d_in[18];
    const float* pd4     = (const float*)d_in[19];
    float* out = (float*)d_out;

    float* wsf    = (float*)d_ws;
    float* featsC = wsf;                       // 131072
    float* p1     = featsC + 131072;           // 2048
    float* W4     = p1 + 2048;                 // 1024*512*4 = 2097152
    unsigned int* G4 = (unsigned int*)(W4 + 2097152);  // 524288
    float* Fbuf   = (float*)G4 + 524288;       // 1024*6272 = 6422528
    float* OG     = Fbuf + 1024*6272;          // 131072
    float* outBuf = OG + 131072;               // 131072
    float* Bm0    = outBuf + 131072;           // 6272*64
    float* Bm1    = Bm0 + 6272*64;             // 3136*64
    float* Bm2    = Bm1 + 3136*64;             // 3136*128
    float* Bm3    = Bm2 + 3136*128;            // 6272*64
    float* Bm4    = Bm3 + 6272*64;             // 3136*8

    prep_kernel<<<NPART, 128, 0, stream>>>(p0_enc, v0_enc, p0, v0, a, lift_c0, lift_d0,
                                           featsC, Fbuf, p1);
    pairs_kernel<<<NPART, 256, 0, stream>>>(p1, mask, (float4*)W4, G4);

    {   // expand B matrices (weights-only; cheap, every call)
        int t0 = 6272*64; expand_kernel<<<(t0+255)/256, 256, 0, stream>>>(Wc0, Wd0, pc4, pd4, Bm0, 16,  64, t0, 1);
        int t1 = 3136*64; expand_kernel<<<(t1+255)/256, 256, 0, stream>>>(Wc1, Wd1, pc4, pd4, Bm1,  8,  64, t1, 0);
        int t2 = 3136*128;expand_kernel<<<(t2+255)/256, 256, 0, stream>>>(Wc2, Wd2, pc4, pd4, Bm2,  8, 128, t2, 0);
        int t3 = 6272*64; expand_kernel<<<(t3+255)/256, 256, 0, stream>>>(Wc3, Wd3, pc4, pd4, Bm3, 16,  64, t3, 0);
        int t4 = 3136*8;  expand_kernel<<<(t4+255)/256, 256, 0, stream>>>(Wc4, Wd4, pc4, pd4, Bm4,  8,   8, t4, 2);
    }

    // Layer 0  (C8=128, Krow=6272, O=8 via concat block-diag B)
    aggregate_kernel<128><<<NPART, 64, 0, stream>>>(featsC, 128, (float4*)W4, G4, Fbuf, 6272);
    gemm16<64><<<128, 256, 0, stream>>>(Fbuf, 6272, Bm0, OG);
    epilogue_kernel<<<(NPART*8+63)/64, 64, 0, stream>>>(OG, 8, 0, outBuf, Fbuf + 3072, 3136);
    // Layer 1  (C8=64, residual)
    aggregate_kernel<64><<<NPART, 64, 0, stream>>>(Fbuf + 3072, 3136, (float4*)W4, G4, Fbuf, 3136);
    gemm16<64><<<128, 256, 0, stream>>>(Fbuf, 3136, Bm1, OG);
    epilogue_kernel<<<(NPART*8+63)/64, 64, 0, stream>>>(OG, 8, 1, outBuf, Fbuf + 3072, 3136);
    // Layer 2  (C8=64 -> O=16)
    aggregate_kernel<64><<<NPART, 64, 0, stream>>>(Fbuf + 3072, 3136, (float4*)W4, G4, Fbuf, 3136);
    gemm16<128><<<128, 256, 0, stream>>>(Fbuf, 3136, Bm2, OG);
    epilogue_kernel<<<(NPART*16+63)/64, 64, 0, stream>>>(OG, 16, 0, outBuf, Fbuf + 6144, 6272);
    // Layer 3  (C8=128 -> O=8)
    aggregate_kernel<128><<<NPART, 64, 0, stream>>>(Fbuf + 6144, 6272, (float4*)W4, G4, Fbuf, 6272);
    gemm16<64><<<128, 256, 0, stream>>>(Fbuf, 6272, Bm3, OG);
    epilogue_kernel<<<(NPART*8+63)/64, 64, 0, stream>>>(OG, 8, 0, outBuf, Fbuf + 3072, 3136);
    // Layer 4  (C8=64 -> 3 channels, proj folded into B; cols 0..5 used)
    aggregate_kernel<64><<<NPART, 64, 0, stream>>>(Fbuf + 3072, 3136, (float4*)W4, G4, Fbuf, 3136);
    gemm16<8><<<128, 256, 0, stream>>>(Fbuf, 3136, Bm4, OG);
    final_kernel<<<4, 256, 0, stream>>>(OG, p1, p0, out);
}

// Round 4
// 671.354 us; speedup vs baseline: 2.2864x; 2.2864x over previous
//
#include <hip/hip_runtime.h>

#define NPART 1024
#define NNB   512

// ---------------------------------------------------------------- prep
__global__ void prep_kernel(const float* __restrict__ p0_enc, const float* __restrict__ v0_enc,
                            const float* __restrict__ p0, const float* __restrict__ v0,
                            const float* __restrict__ a, const float* __restrict__ liftc,
                            const float* __restrict__ liftd,
                            float* __restrict__ featsC, float* __restrict__ Fbuf,
                            float* __restrict__ p1out)
{
    int p = blockIdx.x;          // b*N + i
    int t = threadIdx.x;         // 128 threads: c*8 + m
    int c = t >> 3, m = t & 7;
    float v0x = v0[p*2+0], v0y = v0[p*2+1];
    float ax  = a[p*2+0],  ay  = a[p*2+1];
    float p0x = p0[p*2+0], p0y = p0[p*2+1];
    float v1x = v0x + ax, v1y = v0y + ay;
    float p1x = p0x + 0.5f*(v0x + v1x), p1y = p0y + 0.5f*(v0y + v1y);
    float vx, vy;
    if (c == 0)      { vx = v1x; vy = v1y; }
    else if (c == 1) { vx = p1x; vy = p1y; }
    else if (c < 9)  { vx = v0_enc[(p*7 + (c-2))*2+0]; vy = v0_enc[(p*7 + (c-2))*2+1]; }
    else             { vx = p0_enc[(p*7 + (c-9))*2+0]; vy = p0_enc[(p*7 + (c-9))*2+1]; }
    float th = (float)m * 0.7853981633974483f;
    float cs = cosf(th), sn = sinf(th);
    float lc0 = liftc[0], lc1 = liftc[1];
    float ld0 = liftd[0], ld1 = liftd[1];
    featsC[p*128 + t]        = vx*(lc0*cs - lc1*sn) + vy*(lc0*sn + lc1*cs);
    Fbuf[p*6272 + 6144 + t]  = vx*(ld0*cs - ld1*sn) + vy*(ld0*sn + ld1*cs);  // layer-0 dense tail
    if (t == 0) { p1out[p*2+0] = p1x; p1out[p*2+1] = p1y; }
}

// ---------------------------------------------------------------- pair weights, COMPACTED
// Meta bits: [0:9)=j, [9:13)=t0, [13:15)=r0
__global__ void pairs_kernel(const float* __restrict__ p1, const float* __restrict__ mask,
                             float4* __restrict__ W4c, unsigned short* __restrict__ Meta,
                             int* __restrict__ counts)
{
    int p  = blockIdx.x;          // b*N + i
    int b  = p >> 9;
    int ii = p & 511;
    int tid = threadIdx.x;        // 256
    __shared__ float red[256];
    __shared__ float denomS;
    __shared__ int lcnt;
    if (tid == 0) lcnt = 0;
    float pix = p1[p*2+0], piy = p1[p*2+1];
    float relx[2], rely[2], dd[2], ww[2];
#pragma unroll
    for (int q = 0; q < 2; ++q) {
        int j  = tid + q*256;
        int jr = b*NNB + j;
        float rx = p1[jr*2+0] - pix;
        float ry = p1[jr*2+1] - piy;
        float d  = sqrtf(rx*rx + ry*ry + 1e-12f) * (1.0f/40.0f);
        float t1 = fmaxf(1.0f - d*d, 0.0f);
        float w  = t1*t1*t1 * mask[jr];
        relx[q] = rx; rely[q] = ry; dd[q] = d; ww[q] = w;
    }
    red[tid] = ww[0] + ww[1];
    __syncthreads();
    for (int s = 128; s > 0; s >>= 1) {
        if (tid < s) red[tid] += red[tid+s];
        __syncthreads();
    }
    if (tid == 0) denomS = 1.0f / (red[0] + 1e-6f);
    __syncthreads();
    float dinv = denomS;
#pragma unroll
    for (int q = 0; q < 2; ++q) {
        int j  = tid + q*256;
        if (ww[q] == 0.0f) continue;
        float wb = ww[q] * dinv;
        float d  = dd[q];
        float rc  = fminf(fmaxf(d*3.0f - 0.5f, 0.0f), 2.0f);
        float r0f = floorf(rc);
        float wr  = rc - r0f;
        int r0 = (int)r0f;
        float rx = (j == ii) ? 1.0f : relx[q];
        float ry = (j == ii) ? 0.0f : rely[q];
        float ang = atan2f(ry, rx);
        if (ang < 0.0f) ang += 6.283185307179586f;
        float tc  = ang * 2.546479089470325f;   // *16/(2*pi)
        float t0f = floorf(tc);
        float wt  = tc - t0f;
        int t0  = ((int)t0f) & 15;              // tc==16 edge -> bin 0 like ref's %16
        float4 wv;
        wv.x = wb * (1.0f-wr) * (1.0f-wt);
        wv.y = wb * (1.0f-wr) * wt;
        wv.z = wb * wr * (1.0f-wt);
        wv.w = wb * wr * wt;
        int slot = atomicAdd(&lcnt, 1);
        W4c[p*NNB + slot] = wv;
        Meta[p*NNB + slot] = (unsigned short)(j | (t0 << 9) | (r0 << 13));
    }
    __syncthreads();
    if (tid == 0) counts[p] = lcnt;
}

// ---------------------------------------------------------------- sparse aggregation, pipelined
template<int C8>
__global__ __launch_bounds__(64) void aggregate_kernel(const float* __restrict__ actsrc, int actStride,
                                                       const float4* __restrict__ W4c,
                                                       const unsigned short* __restrict__ Meta,
                                                       const int* __restrict__ counts,
                                                       float* __restrict__ Fbuf, int Krow)
{
    __shared__ float Fs[48*C8];
    __shared__ float4 Ws[NNB];
    __shared__ unsigned short Ms[NNB];
    int p = blockIdx.x;
    int pbase = p & ~511;            // b*N
    int tid = threadIdx.x;
    int cnt = counts[p];
    for (int i = tid; i < 48*C8; i += 64) Fs[i] = 0.0f;
    for (int i = tid; i < cnt; i += 64) { Ws[i] = W4c[p*NNB + i]; Ms[i] = Meta[p*NNB + i]; }
    __syncthreads();

    if (C8 == 128) {
        float2* F2 = (float2*)Fs;
        float2 r0 = {0,0}, r1 = {0,0};
        if (cnt > 0) r0 = ((const float2*)(actsrc + (size_t)(pbase + (Ms[0]&511))*actStride))[tid];
        if (cnt > 1) r1 = ((const float2*)(actsrc + (size_t)(pbase + (Ms[1]&511))*actStride))[tid];
        for (int s = 0; s < cnt; s += 2) {
            float2 rc0 = r0, rc1 = r1;
            if (s+2 < cnt) r0 = ((const float2*)(actsrc + (size_t)(pbase + (Ms[s+2]&511))*actStride))[tid];
            if (s+3 < cnt) r1 = ((const float2*)(actsrc + (size_t)(pbase + (Ms[s+3]&511))*actStride))[tid];
            {
                float4 w = Ws[s]; unsigned int mt = Ms[s];
                int t0 = (mt>>9)&15, rr0 = (mt>>13)&3, rr1 = min(rr0+1,2), t1i = (t0+1)&15;
                int b0 = rr0*16+t0, b1 = rr0*16+t1i, b2 = rr1*16+t0, b3 = rr1*16+t1i;
                float2 v;
                v = F2[b0*64+tid]; v.x += w.x*rc0.x; v.y += w.x*rc0.y; F2[b0*64+tid] = v;
                v = F2[b1*64+tid]; v.x += w.y*rc0.x; v.y += w.y*rc0.y; F2[b1*64+tid] = v;
                v = F2[b2*64+tid]; v.x += w.z*rc0.x; v.y += w.z*rc0.y; F2[b2*64+tid] = v;
                v = F2[b3*64+tid]; v.x += w.w*rc0.x; v.y += w.w*rc0.y; F2[b3*64+tid] = v;
            }
            if (s+1 < cnt) {
                float4 w = Ws[s+1]; unsigned int mt = Ms[s+1];
                int t0 = (mt>>9)&15, rr0 = (mt>>13)&3, rr1 = min(rr0+1,2), t1i = (t0+1)&15;
                int b0 = rr0*16+t0, b1 = rr0*16+t1i, b2 = rr1*16+t0, b3 = rr1*16+t1i;
                float2 v;
                v = F2[b0*64+tid]; v.x += w.x*rc1.x; v.y += w.x*rc1.y; F2[b0*64+tid] = v;
                v = F2[b1*64+tid]; v.x += w.y*rc1.x; v.y += w.y*rc1.y; F2[b1*64+tid] = v;
                v = F2[b2*64+tid]; v.x += w.z*rc1.x; v.y += w.z*rc1.y; F2[b2*64+tid] = v;
                v = F2[b3*64+tid]; v.x += w.w*rc1.x; v.y += w.w*rc1.y; F2[b3*64+tid] = v;
            }
        }
    } else {
        float r0 = 0, r1 = 0;
        if (cnt > 0) r0 = (actsrc + (size_t)(pbase + (Ms[0]&511))*actStride)[tid];
        if (cnt > 1) r1 = (actsrc + (size_t)(pbase + (Ms[1]&511))*actStride)[tid];
        for (int s = 0; s < cnt; s += 2) {
            float rc0 = r0, rc1 = r1;
            if (s+2 < cnt) r0 = (actsrc + (size_t)(pbase + (Ms[s+2]&511))*actStride)[tid];
            if (s+3 < cnt) r1 = (actsrc + (size_t)(pbase + (Ms[s+3]&511))*actStride)[tid];
            {
                float4 w = Ws[s]; unsigned int mt = Ms[s];
                int t0 = (mt>>9)&15, rr0 = (mt>>13)&3, rr1 = min(rr0+1,2), t1i = (t0+1)&15;
                Fs[(rr0*16+t0 )*C8+tid] += w.x*rc0;
                Fs[(rr0*16+t1i)*C8+tid] += w.y*rc0;
                Fs[(rr1*16+t0 )*C8+tid] += w.z*rc0;
                Fs[(rr1*16+t1i)*C8+tid] += w.w*rc0;
            }
            if (s+1 < cnt) {
                float4 w = Ws[s+1]; unsigned int mt = Ms[s+1];
                int t0 = (mt>>9)&15, rr0 = (mt>>13)&3, rr1 = min(rr0+1,2), t1i = (t0+1)&15;
                Fs[(rr0*16+t0 )*C8+tid] += w.x*rc1;
                Fs[(rr0*16+t1i)*C8+tid] += w.y*rc1;
                Fs[(rr1*16+t0 )*C8+tid] += w.z*rc1;
                Fs[(rr1*16+t1i)*C8+tid] += w.w*rc1;
            }
        }
    }
    __syncthreads();
    float* dst = Fbuf + (size_t)p * Krow;
    const float4* Fsv = (const float4*)Fs;
    float4* dv = (float4*)dst;
    for (int i = tid; i < 48*C8/4; i += 64) dv[i] = Fsv[i];
}

// ---------------------------------------------------------------- expand weights into B matrices
__global__ void expand_kernel(const float* __restrict__ Wc, const float* __restrict__ Wd,
                              const float* __restrict__ pc4, const float* __restrict__ pd4,
                              float* __restrict__ Bm, int C, int O8, int total, int mode)
{
    int e = blockIdx.x*blockDim.x + threadIdx.x;
    if (e >= total) return;
    int col = e % O8;
    int k   = e / O8;
    int C8  = C*8;
    bool conv = (k < 48*C8);
    int cc, nn, rr = 0, tt = 0;
    if (conv) {
        int g = k / C8, rem = k - g*C8;
        cc = rem >> 3; nn = rem & 7; rr = g >> 4; tt = g & 15;
    } else {
        int rem = k - 48*C8;
        cc = rem >> 3; nn = rem & 7;
    }
    float val = 0.0f;
    if (mode == 0) {
        int o = col >> 3, m = col & 7;
        if (conv) val = Wc[(((o*C + cc)*8 + ((nn - m) & 7))*3 + rr)*16 + ((tt - 2*m) & 15)];
        else      val = Wd[(o*C + cc)*8 + ((m - nn) & 7)];
    } else if (mode == 1) {
        int o = col >> 3, m = col & 7;
        if (col < 32) { if (conv)  val = Wc[(((o*C + cc)*8 + ((nn - m)&7))*3 + rr)*16 + ((tt - 2*m)&15)]; }
        else          { if (!conv) val = Wd[((o-4)*C + cc)*8 + ((m - nn)&7)]; }
    } else {
        if (col < 6) {
            int co = col >> 1, aa = col & 1;
            float s0 = conv ? pc4[0] : pd4[0];
            float s1 = conv ? pc4[1] : pd4[1];
#pragma unroll
            for (int m = 0; m < 8; ++m) {
                float th = (float)m * 0.7853981633974483f;
                float csv = cosf(th), snv = sinf(th);
                float bas = (aa == 0) ? (s0*csv - s1*snv) : (s0*snv + s1*csv);
                float wv;
                if (conv) wv = Wc[(((co*C + cc)*8 + ((nn - m)&7))*3 + rr)*16 + ((tt - 2*m)&15)];
                else      wv = Wd[(co*C + cc)*8 + ((m - nn)&7)];
                val += wv * bas;
            }
        }
    }
    Bm[e] = val;
}

// ---------------------------------------------------------------- split-K register-tiled f32 GEMM
// C[1024][N] = A[1024][Kdim] * B[Kdim][N]; grid = (16 rowtiles, S splits), KC=448
// block: 256 threads = 16x16, thread tile 4 rows x CT cols. Partials to Cpart[split][1024][N].
template<int N>
__global__ __launch_bounds__(256) void gemm_tile(const float* __restrict__ A, int Kdim,
                                                 const float* __restrict__ B,
                                                 float* __restrict__ Cpart)
{
    constexpr int CT = N/16;               // 1, 4, 8
    __shared__ float As[32][68];           // k-major [kk][row], padded
    __shared__ float Bs[32][N];
    int tid = threadIdx.x;
    int tr = tid & 15, tc = tid >> 4;
    int m0 = blockIdx.x * 64;
    int k0base = blockIdx.y * 448;
    float acc[4][CT];
#pragma unroll
    for (int i = 0; i < 4; ++i)
#pragma unroll
        for (int u = 0; u < CT; ++u) acc[i][u] = 0.0f;

    int ar = tid >> 2, aq = (tid & 3) * 8;
    for (int k0 = 0; k0 < 448; k0 += 32) {
        const float* Ap = A + (size_t)(m0 + ar)*Kdim + k0base + k0 + aq;
        float4 av0 = *(const float4*)(Ap);
        float4 av1 = *(const float4*)(Ap + 4);
        As[aq+0][ar] = av0.x; As[aq+1][ar] = av0.y; As[aq+2][ar] = av0.z; As[aq+3][ar] = av0.w;
        As[aq+4][ar] = av1.x; As[aq+5][ar] = av1.y; As[aq+6][ar] = av1.z; As[aq+7][ar] = av1.w;
#pragma unroll
        for (int u = 0; u < (8*N + 255)/256; ++u) {
            int idx = tid + 256*u;
            if (idx < 8*N) {
                int row = idx / (N/4), c4 = idx % (N/4);
                *(float4*)&Bs[row][c4*4] = *(const float4*)(B + (size_t)(k0base + k0 + row)*N + c4*4);
            }
        }
        __syncthreads();
#pragma unroll
        for (int kk = 0; kk < 32; ++kk) {
            float4 a4 = *(const float4*)&As[kk][tr*4];
            if (CT == 1) {
                float bv = Bs[kk][tc];
                acc[0][0] += a4.x*bv; acc[1][0] += a4.y*bv;
                acc[2][0] += a4.z*bv; acc[3][0] += a4.w*bv;
            } else {
#pragma unroll
                for (int uu = 0; uu < CT; uu += 4) {
                    float4 b4 = *(const float4*)&Bs[kk][tc*CT + uu];
                    acc[0][uu+0] += a4.x*b4.x; acc[0][uu+1] += a4.x*b4.y; acc[0][uu+2] += a4.x*b4.z; acc[0][uu+3] += a4.x*b4.w;
                    acc[1][uu+0] += a4.y*b4.x; acc[1][uu+1] += a4.y*b4.y; acc[1][uu+2] += a4.y*b4.z; acc[1][uu+3] += a4.y*b4.w;
                    acc[2][uu+0] += a4.z*b4.x; acc[2][uu+1] += a4.z*b4.y; acc[2][uu+2] += a4.z*b4.z; acc[2][uu+3] += a4.z*b4.w;
                    acc[3][uu+0] += a4.w*b4.x; acc[3][uu+1] += a4.w*b4.y; acc[3][uu+2] += a4.w*b4.z; acc[3][uu+3] += a4.w*b4.w;
                }
            }
        }
        __syncthreads();
    }
    float* Cp = Cpart + ((size_t)blockIdx.y*1024 + m0)*N;
#pragma unroll
    for (int i = 0; i < 4; ++i)
#pragma unroll
        for (int u = 0; u < CT; ++u)
            Cp[(size_t)(tr*4 + i)*N + tc*CT + u] = acc[i][u];
}

// ---------------------------------------------------------------- epilogue: split-reduce + residual + mag_act
__global__ void epilogue_kernel(const float* __restrict__ Cpart, int S, int O, int res,
                                float* __restrict__ outBuf, float* __restrict__ actDst, int actStride)
{
    int id = blockIdx.x*blockDim.x + threadIdx.x;
    if (id >= NPART*O) return;
    int p = id / O, c = id % O;
    int O8 = O*8;
    float x[8];
#pragma unroll
    for (int m = 0; m < 8; ++m) x[m] = 0.0f;
    for (int s = 0; s < S; ++s) {
        const float4* q = (const float4*)(Cpart + ((size_t)(s*1024 + p))*O8 + c*8);
        float4 u0 = q[0], u1 = q[1];
        x[0]+=u0.x; x[1]+=u0.y; x[2]+=u0.z; x[3]+=u0.w;
        x[4]+=u1.x; x[5]+=u1.y; x[6]+=u1.z; x[7]+=u1.w;
    }
    float* ob = outBuf + (size_t)p*O8 + c*8;
    float mag = 1e-6f;
#pragma unroll
    for (int m = 0; m < 8; ++m) {
        float v = x[m];
        if (res) v += ob[m];
        x[m] = v; mag += v*v;
    }
#pragma unroll
    for (int m = 0; m < 8; ++m) ob[m] = x[m];
    float sc = fmaxf(mag - 0.2f, 0.0f) / mag;
    float* ad = actDst + (size_t)p*actStride + c*8;
#pragma unroll
    for (int m = 0; m < 8; ++m) ad[m] = x[m]*sc;
}

// ---------------------------------------------------------------- final outputs (S=7, N=16 partials)
__global__ void final_kernel(const float* __restrict__ Cpart, const float* __restrict__ p1,
                             const float* __restrict__ p0, float* __restrict__ out)
{
    int p = blockIdx.x*blockDim.x + threadIdx.x;
    if (p >= NPART) return;
    float c[6];
#pragma unroll
    for (int t = 0; t < 6; ++t) c[t] = 0.0f;
    for (int s = 0; s < 7; ++s) {
        const float* q = Cpart + ((size_t)(s*1024 + p))*16;
#pragma unroll
        for (int t = 0; t < 6; ++t) c[t] += q[t];
    }
    const float sc = 0.0078125f;  // 1/128
#pragma unroll
    for (int t = 0; t < 6; ++t) c[t] *= sc;
    float pcx = p1[p*2+0] + c[0], pcy = p1[p*2+1] + c[1];
    out[p*2+0] = pcx; out[p*2+1] = pcy;
    out[2048 + p*2+0] = pcx - p0[p*2+0];
    out[2048 + p*2+1] = pcy - p0[p*2+1];
    out[4096 + p*4+0] = c[2]; out[4096 + p*4+1] = c[3];
    out[4096 + p*4+2] = c[4]; out[4096 + p*4+3] = c[5];
}

// ---------------------------------------------------------------- launch
extern "C" void kernel_launch(void* const* d_in, const int* in_sizes, int n_in,
                              void* d_out, int out_size, void* d_ws, size_t ws_size,
                              hipStream_t stream)
{
    const float* p0_enc  = (const float*)d_in[0];
    const float* v0_enc  = (const float*)d_in[1];
    const float* p0      = (const float*)d_in[2];
    const float* v0      = (const float*)d_in[3];
    const float* a       = (const float*)d_in[4];
    const float* mask    = (const float*)d_in[5];
    const float* lift_c0 = (const float*)d_in[6];
    const float* Wc0     = (const float*)d_in[7];
    const float* lift_d0 = (const float*)d_in[8];
    const float* Wd0     = (const float*)d_in[9];
    const float* Wc1     = (const float*)d_in[10];
    const float* Wd1     = (const float*)d_in[11];
    const float* Wc2     = (const float*)d_in[12];
    const float* Wd2     = (const float*)d_in[13];
    const float* Wc3     = (const float*)d_in[14];
    const float* Wd3     = (const float*)d_in[15];
    const float* Wc4     = (const float*)d_in[16];
    const float* pc4     = (const float*)d_in[17];
    const float* Wd4     = (const float*)d_in[18];
    const float* pd4     = (const float*)d_in[19];
    float* out = (float*)d_out;

    float* wsf    = (float*)d_ws;
    float* featsC = wsf;                               // 131072
    float* p1     = featsC + 131072;                   // 2048
    float* W4c    = p1 + 2048;                         // 2097152 (float4[1024*512])
    unsigned short* Meta = (unsigned short*)(W4c + 2097152);   // 524288 ushort = 262144 floats
    int*   counts = (int*)(W4c + 2097152 + 262144);    // 1024
    float* Fbuf   = (float*)counts + 1024;             // 6422528
    float* Cpart  = Fbuf + 1024*6272;                  // 917504 (max 14*1024*64 / 7*1024*128)
    float* outBuf = Cpart + 917504;                    // 131072
    float* Bm0    = outBuf + 131072;                   // 6272*64
    float* Bm1    = Bm0 + 6272*64;                     // 3136*64
    float* Bm2    = Bm1 + 3136*64;                     // 3136*128
    float* Bm3    = Bm2 + 3136*128;                    // 6272*64
    float* Bm4    = Bm3 + 6272*64;                     // 3136*16

    prep_kernel<<<NPART, 128, 0, stream>>>(p0_enc, v0_enc, p0, v0, a, lift_c0, lift_d0,
                                           featsC, Fbuf, p1);
    pairs_kernel<<<NPART, 256, 0, stream>>>(p1, mask, (float4*)W4c, Meta, counts);

    {   // expand B matrices
        int t0 = 6272*64;  expand_kernel<<<(t0+255)/256, 256, 0, stream>>>(Wc0, Wd0, pc4, pd4, Bm0, 16,  64, t0, 1);
        int t1 = 3136*64;  expand_kernel<<<(t1+255)/256, 256, 0, stream>>>(Wc1, Wd1, pc4, pd4, Bm1,  8,  64, t1, 0);
        int t2 = 3136*128; expand_kernel<<<(t2+255)/256, 256, 0, stream>>>(Wc2, Wd2, pc4, pd4, Bm2,  8, 128, t2, 0);
        int t3 = 6272*64;  expand_kernel<<<(t3+255)/256, 256, 0, stream>>>(Wc3, Wd3, pc4, pd4, Bm3, 16,  64, t3, 0);
        int t4 = 3136*16;  expand_kernel<<<(t4+255)/256, 256, 0, stream>>>(Wc4, Wd4, pc4, pd4, Bm4,  8,  16, t4, 2);
    }

    // Layer 0  (C8=128, K=6272, S=14)
    aggregate_kernel<128><<<NPART, 64, 0, stream>>>(featsC, 128, (float4*)W4c, Meta, counts, Fbuf, 6272);
    gemm_tile<64><<<dim3(16,14), 256, 0, stream>>>(Fbuf, 6272, Bm0, Cpart);
    epilogue_kernel<<<(NPART*8+63)/64, 64, 0, stream>>>(Cpart, 14, 8, 0, outBuf, Fbuf + 3072, 3136);
    // Layer 1  (C8=64, K=3136, S=7, residual)
    aggregate_kernel<64><<<NPART, 64, 0, stream>>>(Fbuf + 3072, 3136, (float4*)W4c, Meta, counts, Fbuf, 3136);
    gemm_tile<64><<<dim3(16,7), 256, 0, stream>>>(Fbuf, 3136, Bm1, Cpart);
    epilogue_kernel<<<(NPART*8+63)/64, 64, 0, stream>>>(Cpart, 7, 8, 1, outBuf, Fbuf + 3072, 3136);
    // Layer 2  (C8=64 -> O=16)
    aggregate_kernel<64><<<NPART, 64, 0, stream>>>(Fbuf + 3072, 3136, (float4*)W4c, Meta, counts, Fbuf, 3136);
    gemm_tile<128><<<dim3(16,7), 256, 0, stream>>>(Fbuf, 3136, Bm2, Cpart);
    epilogue_kernel<<<(NPART*16+63)/64, 64, 0, stream>>>(Cpart, 7, 16, 0, outBuf, Fbuf + 6144, 6272);
    // Layer 3  (C8=128 -> O=8)
    aggregate_kernel<128><<<NPART, 64, 0, stream>>>(Fbuf + 6144, 6272, (float4*)W4c, Meta, counts, Fbuf, 6272);
    gemm_tile<64><<<dim3(16,14), 256, 0, stream>>>(Fbuf, 6272, Bm3, Cpart);
    epilogue_kernel<<<(NPART*8+63)/64, 64, 0, stream>>>(Cpart, 14, 8, 0, outBuf, Fbuf + 3072, 3136);
    // Layer 4  (C8=64 -> N=16 padded, proj folded)
    aggregate_kernel<64><<<NPART, 64, 0, stream>>>(Fbuf + 3072, 3136, (float4*)W4c, Meta, counts, Fbuf, 3136);
    gemm_tile<16><<<dim3(16,7), 256, 0, stream>>>(Fbuf, 3136, Bm4, Cpart);
    final_kernel<<<4, 256, 0, stream>>>(Cpart, p1, p0, out);
}

// Round 5
// 565.213 us; speedup vs baseline: 2.7158x; 1.1878x over previous
//
#include <hip/hip_runtime.h>

#define NPART 1024
#define NNB   512

// ---------------------------------------------------------------- prep
__global__ void prep_kernel(const float* __restrict__ p0_enc, const float* __restrict__ v0_enc,
                            const float* __restrict__ p0, const float* __restrict__ v0,
                            const float* __restrict__ a, const float* __restrict__ liftc,
                            const float* __restrict__ liftd,
                            float* __restrict__ featsC, float* __restrict__ Fbuf,
                            float* __restrict__ p1out)
{
    int p = blockIdx.x;          // b*N + i
    int t = threadIdx.x;         // 128 threads: c*8 + m
    int c = t >> 3, m = t & 7;
    float v0x = v0[p*2+0], v0y = v0[p*2+1];
    float ax  = a[p*2+0],  ay  = a[p*2+1];
    float p0x = p0[p*2+0], p0y = p0[p*2+1];
    float v1x = v0x + ax, v1y = v0y + ay;
    float p1x = p0x + 0.5f*(v0x + v1x), p1y = p0y + 0.5f*(v0y + v1y);
    float vx, vy;
    if (c == 0)      { vx = v1x; vy = v1y; }
    else if (c == 1) { vx = p1x; vy = p1y; }
    else if (c < 9)  { vx = v0_enc[(p*7 + (c-2))*2+0]; vy = v0_enc[(p*7 + (c-2))*2+1]; }
    else             { vx = p0_enc[(p*7 + (c-9))*2+0]; vy = p0_enc[(p*7 + (c-9))*2+1]; }
    float th = (float)m * 0.7853981633974483f;
    float cs = cosf(th), sn = sinf(th);
    float lc0 = liftc[0], lc1 = liftc[1];
    float ld0 = liftd[0], ld1 = liftd[1];
    featsC[p*128 + t]        = vx*(lc0*cs - lc1*sn) + vy*(lc0*sn + lc1*cs);
    Fbuf[p*6272 + 6144 + t]  = vx*(ld0*cs - ld1*sn) + vy*(ld0*sn + ld1*cs);  // layer-0 dense tail
    if (t == 0) { p1out[p*2+0] = p1x; p1out[p*2+1] = p1y; }
}

// ---------------------------------------------------------------- pair weights, COMPACTED
// Meta bits: [0:9)=j, [9:13)=t0, [13:15)=r0
__global__ void pairs_kernel(const float* __restrict__ p1, const float* __restrict__ mask,
                             float4* __restrict__ W4c, unsigned short* __restrict__ Meta,
                             int* __restrict__ counts)
{
    int p  = blockIdx.x;          // b*N + i
    int b  = p >> 9;
    int ii = p & 511;
    int tid = threadIdx.x;        // 256
    __shared__ float red[256];
    __shared__ float denomS;
    __shared__ int lcnt;
    if (tid == 0) lcnt = 0;
    float pix = p1[p*2+0], piy = p1[p*2+1];
    float relx[2], rely[2], dd[2], ww[2];
#pragma unroll
    for (int q = 0; q < 2; ++q) {
        int j  = tid + q*256;
        int jr = b*NNB + j;
        float rx = p1[jr*2+0] - pix;
        float ry = p1[jr*2+1] - piy;
        float d  = sqrtf(rx*rx + ry*ry + 1e-12f) * (1.0f/40.0f);
        float t1 = fmaxf(1.0f - d*d, 0.0f);
        float w  = t1*t1*t1 * mask[jr];
        relx[q] = rx; rely[q] = ry; dd[q] = d; ww[q] = w;
    }
    red[tid] = ww[0] + ww[1];
    __syncthreads();
    for (int s = 128; s > 0; s >>= 1) {
        if (tid < s) red[tid] += red[tid+s];
        __syncthreads();
    }
    if (tid == 0) denomS = 1.0f / (red[0] + 1e-6f);
    __syncthreads();
    float dinv = denomS;
#pragma unroll
    for (int q = 0; q < 2; ++q) {
        int j  = tid + q*256;
        if (ww[q] == 0.0f) continue;
        float wb = ww[q] * dinv;
        float d  = dd[q];
        float rc  = fminf(fmaxf(d*3.0f - 0.5f, 0.0f), 2.0f);
        float r0f = floorf(rc);
        float wr  = rc - r0f;
        int r0 = (int)r0f;
        float rx = (j == ii) ? 1.0f : relx[q];
        float ry = (j == ii) ? 0.0f : rely[q];
        float ang = atan2f(ry, rx);
        if (ang < 0.0f) ang += 6.283185307179586f;
        float tc  = ang * 2.546479089470325f;   // *16/(2*pi)
        float t0f = floorf(tc);
        float wt  = tc - t0f;
        int t0  = ((int)t0f) & 15;              // tc==16 edge -> bin 0 like ref's %16
        float4 wv;
        wv.x = wb * (1.0f-wr) * (1.0f-wt);
        wv.y = wb * (1.0f-wr) * wt;
        wv.z = wb * wr * (1.0f-wt);
        wv.w = wb * wr * wt;
        int slot = atomicAdd(&lcnt, 1);
        W4c[p*NNB + slot] = wv;
        Meta[p*NNB + slot] = (unsigned short)(j | (t0 << 9) | (r0 << 13));
    }
    __syncthreads();
    if (tid == 0) counts[p] = lcnt;
}

// ---------------------------------------------------------------- sparse aggregation, bin-parity partition
// 4 waves per block; wave (rpar,tpar) owns bins with r%2==rpar, t%2==tpar.
// Each entry has exactly one bin per parity class (r0=r1=2 case carries weight 0).
template<int C8>
__global__ __launch_bounds__(256) void aggregate_kernel(const float* __restrict__ actsrc, int actStride,
                                                        const float4* __restrict__ W4c,
                                                        const unsigned short* __restrict__ Meta,
                                                        const int* __restrict__ counts,
                                                        float* __restrict__ Fbuf, int Krow)
{
    __shared__ float Fs[48*C8];
    __shared__ float4 Ws[NNB];
    __shared__ unsigned short Ms[NNB];
    int p = blockIdx.x;
    int pbase = p & ~511;            // b*N
    int tid  = threadIdx.x;
    int lane = tid & 63;
    int wv   = tid >> 6;             // 0..3
    int rpar = wv >> 1, tpar = wv & 1;
    int cnt = counts[p];
    {
        float4* Fz = (float4*)Fs;
        for (int i = tid; i < 48*C8/4; i += 256) Fz[i] = make_float4(0.f,0.f,0.f,0.f);
        for (int i = tid; i < cnt; i += 256) { Ws[i] = W4c[p*NNB + i]; Ms[i] = Meta[p*NNB + i]; }
    }
    __syncthreads();

    if (C8 == 128) {
        float2* F2 = (float2*)Fs;
        float2 pf0 = {0,0}, pf1 = {0,0};
        if (cnt > 0) pf0 = ((const float2*)(actsrc + (size_t)(pbase + (Ms[0]&511))*actStride))[lane];
        if (cnt > 1) pf1 = ((const float2*)(actsrc + (size_t)(pbase + (Ms[1]&511))*actStride))[lane];
        for (int s = 0; s < cnt; ++s) {
            float2 f = pf0; pf0 = pf1;
            if (s + 2 < cnt) pf1 = ((const float2*)(actsrc + (size_t)(pbase + (Ms[s+2]&511))*actStride))[lane];
            unsigned int mt = Ms[s];
            float4 w4 = Ws[s];
            int t0 = (mt>>9)&15, r0 = (mt>>13)&3;
            int r1 = min(r0+1, 2), t1 = (t0+1)&15;
            bool rIsR0 = ((r0 & 1) == rpar);
            bool tIsT0 = ((t0 & 1) == tpar);
            int rsel = rIsR0 ? r0 : r1;
            int tsel = tIsT0 ? t0 : t1;
            float wgt = rIsR0 ? (tIsT0 ? w4.x : w4.y) : (tIsT0 ? w4.z : w4.w);
            int bin = rsel*16 + tsel;
            float2 v = F2[bin*(C8/2) + lane];
            v.x += wgt*f.x; v.y += wgt*f.y;
            F2[bin*(C8/2) + lane] = v;
        }
    } else {
        float pf0 = 0, pf1 = 0;
        if (cnt > 0) pf0 = (actsrc + (size_t)(pbase + (Ms[0]&511))*actStride)[lane];
        if (cnt > 1) pf1 = (actsrc + (size_t)(pbase + (Ms[1]&511))*actStride)[lane];
        for (int s = 0; s < cnt; ++s) {
            float f = pf0; pf0 = pf1;
            if (s + 2 < cnt) pf1 = (actsrc + (size_t)(pbase + (Ms[s+2]&511))*actStride)[lane];
            unsigned int mt = Ms[s];
            float4 w4 = Ws[s];
            int t0 = (mt>>9)&15, r0 = (mt>>13)&3;
            int r1 = min(r0+1, 2), t1 = (t0+1)&15;
            bool rIsR0 = ((r0 & 1) == rpar);
            bool tIsT0 = ((t0 & 1) == tpar);
            int rsel = rIsR0 ? r0 : r1;
            int tsel = tIsT0 ? t0 : t1;
            float wgt = rIsR0 ? (tIsT0 ? w4.x : w4.y) : (tIsT0 ? w4.z : w4.w);
            int bin = rsel*16 + tsel;
            Fs[bin*C8 + lane] += wgt*f;
        }
    }
    __syncthreads();
    float* dst = Fbuf + (size_t)p * Krow;
    const float4* Fsv = (const float4*)Fs;
    float4* dv = (float4*)dst;
    for (int i = tid; i < 48*C8/4; i += 256) dv[i] = Fsv[i];
}

// ---------------------------------------------------------------- expand weights into B matrices
__global__ void expand_kernel(const float* __restrict__ Wc, const float* __restrict__ Wd,
                              const float* __restrict__ pc4, const float* __restrict__ pd4,
                              float* __restrict__ Bm, int C, int O8, int total, int mode)
{
    int e = blockIdx.x*blockDim.x + threadIdx.x;
    if (e >= total) return;
    int col = e % O8;
    int k   = e / O8;
    int C8  = C*8;
    bool conv = (k < 48*C8);
    int cc, nn, rr = 0, tt = 0;
    if (conv) {
        int g = k / C8, rem = k - g*C8;
        cc = rem >> 3; nn = rem & 7; rr = g >> 4; tt = g & 15;
    } else {
        int rem = k - 48*C8;
        cc = rem >> 3; nn = rem & 7;
    }
    float val = 0.0f;
    if (mode == 0) {
        int o = col >> 3, m = col & 7;
        if (conv) val = Wc[(((o*C + cc)*8 + ((nn - m) & 7))*3 + rr)*16 + ((tt - 2*m) & 15)];
        else      val = Wd[(o*C + cc)*8 + ((m - nn) & 7)];
    } else if (mode == 1) {
        int o = col >> 3, m = col & 7;
        if (col < 32) { if (conv)  val = Wc[(((o*C + cc)*8 + ((nn - m)&7))*3 + rr)*16 + ((tt - 2*m)&15)]; }
        else          { if (!conv) val = Wd[((o-4)*C + cc)*8 + ((m - nn)&7)]; }
    } else {
        if (col < 6) {
            int co = col >> 1, aa = col & 1;
            float s0 = conv ? pc4[0] : pd4[0];
            float s1 = conv ? pc4[1] : pd4[1];
#pragma unroll
            for (int m = 0; m < 8; ++m) {
                float th = (float)m * 0.7853981633974483f;
                float csv = cosf(th), snv = sinf(th);
                float bas = (aa == 0) ? (s0*csv - s1*snv) : (s0*snv + s1*csv);
                float wv;
                if (conv) wv = Wc[(((co*C + cc)*8 + ((nn - m)&7))*3 + rr)*16 + ((tt - 2*m)&15)];
                else      wv = Wd[(co*C + cc)*8 + ((m - nn)&7)];
                val += wv * bas;
            }
        }
    }
    Bm[e] = val;
}

// ---------------------------------------------------------------- split-K register-tiled f32 GEMM
// C[1024][N] = A[1024][Kdim] * B[Kdim][N]; grid = (16 rowtiles, S splits), KC=448
// block: 256 threads = 16x16, thread tile 4 rows x CT cols. Partials to Cpart[split][1024][N].
template<int N>
__global__ __launch_bounds__(256) void gemm_tile(const float* __restrict__ A, int Kdim,
                                                 const float* __restrict__ B,
                                                 float* __restrict__ Cpart)
{
    constexpr int CT = N/16;               // 1, 4, 8
    __shared__ float As[32][68];           // k-major [kk][row], padded
    __shared__ float Bs[32][N];
    int tid = threadIdx.x;
    int tr = tid & 15, tc = tid >> 4;
    int m0 = blockIdx.x * 64;
    int k0base = blockIdx.y * 448;
    float acc[4][CT];
#pragma unroll
    for (int i = 0; i < 4; ++i)
#pragma unroll
        for (int u = 0; u < CT; ++u) acc[i][u] = 0.0f;

    int ar = tid >> 2, aq = (tid & 3) * 8;
    for (int k0 = 0; k0 < 448; k0 += 32) {
        const float* Ap = A + (size_t)(m0 + ar)*Kdim + k0base + k0 + aq;
        float4 av0 = *(const float4*)(Ap);
        float4 av1 = *(const float4*)(Ap + 4);
        As[aq+0][ar] = av0.x; As[aq+1][ar] = av0.y; As[aq+2][ar] = av0.z; As[aq+3][ar] = av0.w;
        As[aq+4][ar] = av1.x; As[aq+5][ar] = av1.y; As[aq+6][ar] = av1.z; As[aq+7][ar] = av1.w;
#pragma unroll
        for (int u = 0; u < (8*N + 255)/256; ++u) {
            int idx = tid + 256*u;
            if (idx < 8*N) {
                int row = idx / (N/4), c4 = idx % (N/4);
                *(float4*)&Bs[row][c4*4] = *(const float4*)(B + (size_t)(k0base + k0 + row)*N + c4*4);
            }
        }
        __syncthreads();
#pragma unroll
        for (int kk = 0; kk < 32; ++kk) {
            float4 a4 = *(const float4*)&As[kk][tr*4];
            if (CT == 1) {
                float bv = Bs[kk][tc];
                acc[0][0] += a4.x*bv; acc[1][0] += a4.y*bv;
                acc[2][0] += a4.z*bv; acc[3][0] += a4.w*bv;
            } else {
#pragma unroll
                for (int uu = 0; uu < CT; uu += 4) {
                    float4 b4 = *(const float4*)&Bs[kk][tc*CT + uu];
                    acc[0][uu+0] += a4.x*b4.x; acc[0][uu+1] += a4.x*b4.y; acc[0][uu+2] += a4.x*b4.z; acc[0][uu+3] += a4.x*b4.w;
                    acc[1][uu+0] += a4.y*b4.x; acc[1][uu+1] += a4.y*b4.y; acc[1][uu+2] += a4.y*b4.z; acc[1][uu+3] += a4.y*b4.w;
                    acc[2][uu+0] += a4.z*b4.x; acc[2][uu+1] += a4.z*b4.y; acc[2][uu+2] += a4.z*b4.z; acc[2][uu+3] += a4.z*b4.w;
                    acc[3][uu+0] += a4.w*b4.x; acc[3][uu+1] += a4.w*b4.y; acc[3][uu+2] += a4.w*b4.z; acc[3][uu+3] += a4.w*b4.w;
                }
            }
        }
        __syncthreads();
    }
    float* Cp = Cpart + ((size_t)blockIdx.y*1024 + m0)*N;
#pragma unroll
    for (int i = 0; i < 4; ++i)
#pragma unroll
        for (int u = 0; u < CT; ++u)
            Cp[(size_t)(tr*4 + i)*N + tc*CT + u] = acc[i][u];
}

// ---------------------------------------------------------------- epilogue: split-reduce + residual + mag_act
__global__ void epilogue_kernel(const float* __restrict__ Cpart, int S, int O, int res,
                                float* __restrict__ outBuf, float* __restrict__ actDst, int actStride)
{
    int id = blockIdx.x*blockDim.x + threadIdx.x;
    if (id >= NPART*O) return;
    int p = id / O, c = id % O;
    int O8 = O*8;
    float x[8];
#pragma unroll
    for (int m = 0; m < 8; ++m) x[m] = 0.0f;
    for (int s = 0; s < S; ++s) {
        const float4* q = (const float4*)(Cpart + ((size_t)(s*1024 + p))*O8 + c*8);
        float4 u0 = q[0], u1 = q[1];
        x[0]+=u0.x; x[1]+=u0.y; x[2]+=u0.z; x[3]+=u0.w;
        x[4]+=u1.x; x[5]+=u1.y; x[6]+=u1.z; x[7]+=u1.w;
    }
    float* ob = outBuf + (size_t)p*O8 + c*8;
    float mag = 1e-6f;
#pragma unroll
    for (int m = 0; m < 8; ++m) {
        float v = x[m];
        if (res) v += ob[m];
        x[m] = v; mag += v*v;
    }
#pragma unroll
    for (int m = 0; m < 8; ++m) ob[m] = x[m];
    float sc = fmaxf(mag - 0.2f, 0.0f) / mag;
    float* ad = actDst + (size_t)p*actStride + c*8;
#pragma unroll
    for (int m = 0; m < 8; ++m) ad[m] = x[m]*sc;
}

// ---------------------------------------------------------------- final outputs (S=7, N=16 partials)
__global__ void final_kernel(const float* __restrict__ Cpart, const float* __restrict__ p1,
                             const float* __restrict__ p0, float* __restrict__ out)
{
    int p = blockIdx.x*blockDim.x + threadIdx.x;
    if (p >= NPART) return;
    float c[6];
#pragma unroll
    for (int t = 0; t < 6; ++t) c[t] = 0.0f;
    for (int s = 0; s < 7; ++s) {
        const float* q = Cpart + ((size_t)(s*1024 + p))*16;
#pragma unroll
        for (int t = 0; t < 6; ++t) c[t] += q[t];
    }
    const float sc = 0.0078125f;  // 1/128
#pragma unroll
    for (int t = 0; t < 6; ++t) c[t] *= sc;
    float pcx = p1[p*2+0] + c[0], pcy = p1[p*2+1] + c[1];
    out[p*2+0] = pcx; out[p*2+1] = pcy;
    out[2048 + p*2+0] = pcx - p0[p*2+0];
    out[2048 + p*2+1] = pcy - p0[p*2+1];
    out[4096 + p*4+0] = c[2]; out[4096 + p*4+1] = c[3];
    out[4096 + p*4+2] = c[4]; out[4096 + p*4+3] = c[5];
}

// ---------------------------------------------------------------- launch
extern "C" void kernel_launch(void* const* d_in, const int* in_sizes, int n_in,
                              void* d_out, int out_size, void* d_ws, size_t ws_size,
                              hipStream_t stream)
{
    const float* p0_enc  = (const float*)d_in[0];
    const float* v0_enc  = (const float*)d_in[1];
    const float* p0      = (const float*)d_in[2];
    const float* v0      = (const float*)d_in[3];
    const float* a       = (const float*)d_in[4];
    const float* mask    = (const float*)d_in[5];
    const float* lift_c0 = (const float*)d_in[6];
    const float* Wc0     = (const float*)d_in[7];
    const float* lift_d0 = (const float*)d_in[8];
    const float* Wd0     = (const float*)d_in[9];
    const float* Wc1     = (const float*)d_in[10];
    const float* Wd1     = (const float*)d_in[11];
    const float* Wc2     = (const float*)d_in[12];
    const float* Wd2     = (const float*)d_in[13];
    const float* Wc3     = (const float*)d_in[14];
    const float* Wd3     = (const float*)d_in[15];
    const float* Wc4     = (const float*)d_in[16];
    const float* pc4     = (const float*)d_in[17];
    const float* Wd4     = (const float*)d_in[18];
    const float* pd4     = (const float*)d_in[19];
    float* out = (float*)d_out;

    float* wsf    = (float*)d_ws;
    float* featsC = wsf;                               // 131072
    float* p1     = featsC + 131072;                   // 2048
    float* W4c    = p1 + 2048;                         // 2097152 (float4[1024*512])
    unsigned short* Meta = (unsigned short*)(W4c + 2097152);   // 524288 ushort = 262144 floats
    int*   counts = (int*)(W4c + 2097152 + 262144);    // 1024
    float* Fbuf   = (float*)counts + 1024;             // 6422528
    float* Cpart  = Fbuf + 1024*6272;                  // 917504 (max 14*1024*64 / 7*1024*128)
    float* outBuf = Cpart + 917504;                    // 131072
    float* Bm0    = outBuf + 131072;                   // 6272*64
    float* Bm1    = Bm0 + 6272*64;                     // 3136*64
    float* Bm2    = Bm1 + 3136*64;                     // 3136*128
    float* Bm3    = Bm2 + 3136*128;                    // 6272*64
    float* Bm4    = Bm3 + 6272*64;                     // 3136*16

    prep_kernel<<<NPART, 128, 0, stream>>>(p0_enc, v0_enc, p0, v0, a, lift_c0, lift_d0,
                                           featsC, Fbuf, p1);
    pairs_kernel<<<NPART, 256, 0, stream>>>(p1, mask, (float4*)W4c, Meta, counts);

    {   // expand B matrices
        int t0 = 6272*64;  expand_kernel<<<(t0+255)/256, 256, 0, stream>>>(Wc0, Wd0, pc4, pd4, Bm0, 16,  64, t0, 1);
        int t1 = 3136*64;  expand_kernel<<<(t1+255)/256, 256, 0, stream>>>(Wc1, Wd1, pc4, pd4, Bm1,  8,  64, t1, 0);
        int t2 = 3136*128; expand_kernel<<<(t2+255)/256, 256, 0, stream>>>(Wc2, Wd2, pc4, pd4, Bm2,  8, 128, t2, 0);
        int t3 = 6272*64;  expand_kernel<<<(t3+255)/256, 256, 0, stream>>>(Wc3, Wd3, pc4, pd4, Bm3, 16,  64, t3, 0);
        int t4 = 3136*16;  expand_kernel<<<(t4+255)/256, 256, 0, stream>>>(Wc4, Wd4, pc4, pd4, Bm4,  8,  16, t4, 2);
    }

    // Layer 0  (C8=128, K=6272, S=14)
    aggregate_kernel<128><<<NPART, 256, 0, stream>>>(featsC, 128, (float4*)W4c, Meta, counts, Fbuf, 6272);
    gemm_tile<64><<<dim3(16,14), 256, 0, stream>>>(Fbuf, 6272, Bm0, Cpart);
    epilogue_kernel<<<(NPART*8+63)/64, 64, 0, stream>>>(Cpart, 14, 8, 0, outBuf, Fbuf + 3072, 3136);
    // Layer 1  (C8=64, K=3136, S=7, residual)
    aggregate_kernel<64><<<NPART, 256, 0, stream>>>(Fbuf + 3072, 3136, (float4*)W4c, Meta, counts, Fbuf, 3136);
    gemm_tile<64><<<dim3(16,7), 256, 0, stream>>>(Fbuf, 3136, Bm1, Cpart);
    epilogue_kernel<<<(NPART*8+63)/64, 64, 0, stream>>>(Cpart, 7, 8, 1, outBuf, Fbuf + 3072, 3136);
    // Layer 2  (C8=64 -> O=16)
    aggregate_kernel<64><<<NPART, 256, 0, stream>>>(Fbuf + 3072, 3136, (float4*)W4c, Meta, counts, Fbuf, 3136);
    gemm_tile<128><<<dim3(16,7), 256, 0, stream>>>(Fbuf, 3136, Bm2, Cpart);
    epilogue_kernel<<<(NPART*16+63)/64, 64, 0, stream>>>(Cpart, 7, 16, 0, outBuf, Fbuf + 6144, 6272);
    // Layer 3  (C8=128 -> O=8)
    aggregate_kernel<128><<<NPART, 256, 0, stream>>>(Fbuf + 6144, 6272, (float4*)W4c, Meta, counts, Fbuf, 6272);
    gemm_tile<64><<<dim3(16,14), 256, 0, stream>>>(Fbuf, 6272, Bm3, Cpart);
    epilogue_kernel<<<(NPART*8+63)/64, 64, 0, stream>>>(Cpart, 14, 8, 0, outBuf, Fbuf + 3072, 3136);
    // Layer 4  (C8=64 -> N=16 padded, proj folded)
    aggregate_kernel<64><<<NPART, 256, 0, stream>>>(Fbuf + 3072, 3136, (float4*)W4c, Meta, counts, Fbuf, 3136);
    gemm_tile<16><<<dim3(16,7), 256, 0, stream>>>(Fbuf, 3136, Bm4, Cpart);
    final_kernel<<<4, 256, 0, stream>>>(Cpart, p1, p0, out);
}

// Round 6
// 534.276 us; speedup vs baseline: 2.8730x; 1.0579x over previous
//
#include <hip/hip_runtime.h>

#define NPART 1024
#define NNB   512

// ---------------------------------------------------------------- prep
__global__ void prep_kernel(const float* __restrict__ p0_enc, const float* __restrict__ v0_enc,
                            const float* __restrict__ p0, const float* __restrict__ v0,
                            const float* __restrict__ a, const float* __restrict__ liftc,
                            const float* __restrict__ liftd,
                            float* __restrict__ featsC, float* __restrict__ Fbuf,
                            float* __restrict__ p1out)
{
    int p = blockIdx.x;          // b*N + i
    int t = threadIdx.x;         // 128 threads: c*8 + m
    int c = t >> 3, m = t & 7;
    float v0x = v0[p*2+0], v0y = v0[p*2+1];
    float ax  = a[p*2+0],  ay  = a[p*2+1];
    float p0x = p0[p*2+0], p0y = p0[p*2+1];
    float v1x = v0x + ax, v1y = v0y + ay;
    float p1x = p0x + 0.5f*(v0x + v1x), p1y = p0y + 0.5f*(v0y + v1y);
    float vx, vy;
    if (c == 0)      { vx = v1x; vy = v1y; }
    else if (c == 1) { vx = p1x; vy = p1y; }
    else if (c < 9)  { vx = v0_enc[(p*7 + (c-2))*2+0]; vy = v0_enc[(p*7 + (c-2))*2+1]; }
    else             { vx = p0_enc[(p*7 + (c-9))*2+0]; vy = p0_enc[(p*7 + (c-9))*2+1]; }
    float th = (float)m * 0.7853981633974483f;
    float cs = cosf(th), sn = sinf(th);
    float lc0 = liftc[0], lc1 = liftc[1];
    float ld0 = liftd[0], ld1 = liftd[1];
    featsC[p*128 + t]        = vx*(lc0*cs - lc1*sn) + vy*(lc0*sn + lc1*cs);
    Fbuf[p*6272 + 6144 + t]  = vx*(ld0*cs - ld1*sn) + vy*(ld0*sn + ld1*cs);  // layer-0 dense tail
    if (t == 0) { p1out[p*2+0] = p1x; p1out[p*2+1] = p1y; }
}

// ---------------------------------------------------------------- pair weights, COMPACTED
// Meta bits: [0:9)=j, [9:13)=t0, [13:15)=r0
__global__ void pairs_kernel(const float* __restrict__ p1, const float* __restrict__ mask,
                             float4* __restrict__ W4c, unsigned short* __restrict__ Meta,
                             int* __restrict__ counts)
{
    int p  = blockIdx.x;          // b*N + i
    int b  = p >> 9;
    int ii = p & 511;
    int tid = threadIdx.x;        // 256
    __shared__ float red[256];
    __shared__ float denomS;
    __shared__ int lcnt;
    if (tid == 0) lcnt = 0;
    float pix = p1[p*2+0], piy = p1[p*2+1];
    float relx[2], rely[2], dd[2], ww[2];
#pragma unroll
    for (int q = 0; q < 2; ++q) {
        int j  = tid + q*256;
        int jr = b*NNB + j;
        float rx = p1[jr*2+0] - pix;
        float ry = p1[jr*2+1] - piy;
        float d  = sqrtf(rx*rx + ry*ry + 1e-12f) * (1.0f/40.0f);
        float t1 = fmaxf(1.0f - d*d, 0.0f);
        float w  = t1*t1*t1 * mask[jr];
        relx[q] = rx; rely[q] = ry; dd[q] = d; ww[q] = w;
    }
    red[tid] = ww[0] + ww[1];
    __syncthreads();
    for (int s = 128; s > 0; s >>= 1) {
        if (tid < s) red[tid] += red[tid+s];
        __syncthreads();
    }
    if (tid == 0) denomS = 1.0f / (red[0] + 1e-6f);
    __syncthreads();
    float dinv = denomS;
#pragma unroll
    for (int q = 0; q < 2; ++q) {
        int j  = tid + q*256;
        if (ww[q] == 0.0f) continue;
        float wb = ww[q] * dinv;
        float d  = dd[q];
        float rc  = fminf(fmaxf(d*3.0f - 0.5f, 0.0f), 2.0f);
        float r0f = floorf(rc);
        float wr  = rc - r0f;
        int r0 = (int)r0f;
        float rx = (j == ii) ? 1.0f : relx[q];
        float ry = (j == ii) ? 0.0f : rely[q];
        float ang = atan2f(ry, rx);
        if (ang < 0.0f) ang += 6.283185307179586f;
        float tc  = ang * 2.546479089470325f;   // *16/(2*pi)
        float t0f = floorf(tc);
        float wt  = tc - t0f;
        int t0  = ((int)t0f) & 15;              // tc==16 edge -> bin 0 like ref's %16
        float4 wv;
        wv.x = wb * (1.0f-wr) * (1.0f-wt);
        wv.y = wb * (1.0f-wr) * wt;
        wv.z = wb * wr * (1.0f-wt);
        wv.w = wb * wr * wt;
        int slot = atomicAdd(&lcnt, 1);
        W4c[p*NNB + slot] = wv;
        Meta[p*NNB + slot] = (unsigned short)(j | (t0 << 9) | (r0 << 13));
    }
    __syncthreads();
    if (tid == 0) counts[p] = lcnt;
}

// ---------------------------------------------------------------- sparse aggregation
// 8 waves = 2 entry-groups x 4 parity waves. Group g accumulates into its own Fs[g];
// merged on writeout. Parity wave owns bins with (r%2, t%2) == (rpar, tpar): exactly one
// of the entry's 4 bins per class (r0==r1 clamp case carries zero weight).
template<int C8>
__global__ __launch_bounds__(512) void aggregate_kernel(const float* __restrict__ actsrc, int actStride,
                                                        const float4* __restrict__ W4c,
                                                        const unsigned short* __restrict__ Meta,
                                                        const int* __restrict__ counts,
                                                        float* __restrict__ Fbuf, int Krow)
{
    constexpr bool STAGEW = (C8 == 64);
    __shared__ float Fs[2][48*C8];
    __shared__ float4 Ws[STAGEW ? NNB : 1];
    __shared__ unsigned short Ms[NNB];
    int p = blockIdx.x;
    int pbase = p & ~511;            // b*N
    int tid  = threadIdx.x;
    int lane = tid & 63;
    int wvid = tid >> 6;             // 0..7
    int grp  = wvid >> 2;            // 0..1
    int sub  = wvid & 3;
    int rpar = sub >> 1, tpar = sub & 1;
    int cnt = counts[p];
    {
        float4* Fz = (float4*)&Fs[0][0];
        for (int i = tid; i < 2*48*C8/4; i += 512) Fz[i] = make_float4(0.f,0.f,0.f,0.f);
        for (int i = tid; i < cnt; i += 512) {
            Ms[i] = Meta[p*NNB + i];
            if (STAGEW) Ws[i] = W4c[p*NNB + i];
        }
    }
    __syncthreads();
    int half = (cnt + 1) >> 1;
    int s0 = grp ? half : 0;
    int s1 = grp ? cnt  : half;
    const float4* Wp = W4c + p*NNB;

    if (C8 == 128) {
        float2* F2 = (float2*)&Fs[grp][0];
        float2 pf0 = {0,0}, pf1 = {0,0};
        float4 wA = {0,0,0,0}, wB = {0,0,0,0};
        if (s0 < s1)     { pf0 = ((const float2*)(actsrc + (size_t)(pbase + (Ms[s0]&511))*actStride))[lane];   wA = Wp[s0]; }
        if (s0 + 1 < s1) { pf1 = ((const float2*)(actsrc + (size_t)(pbase + (Ms[s0+1]&511))*actStride))[lane]; wB = Wp[s0+1]; }
        for (int s = s0; s < s1; ++s) {
            float2 f = pf0; pf0 = pf1;
            float4 w4 = wA; wA = wB;
            if (s + 2 < s1) {
                pf1 = ((const float2*)(actsrc + (size_t)(pbase + (Ms[s+2]&511))*actStride))[lane];
                wB  = Wp[s+2];
            }
            unsigned int mt = Ms[s];
            int t0 = (mt>>9)&15, r0 = (mt>>13)&3;
            int r1 = min(r0+1, 2), t1 = (t0+1)&15;
            bool rIsR0 = ((r0 & 1) == rpar);
            bool tIsT0 = ((t0 & 1) == tpar);
            int rsel = rIsR0 ? r0 : r1;
            int tsel = tIsT0 ? t0 : t1;
            float wgt = rIsR0 ? (tIsT0 ? w4.x : w4.y) : (tIsT0 ? w4.z : w4.w);
            int bin = rsel*16 + tsel;
            float2 v = F2[bin*(C8/2) + lane];
            v.x += wgt*f.x; v.y += wgt*f.y;
            F2[bin*(C8/2) + lane] = v;
        }
    } else {
        float* F1 = &Fs[grp][0];
        float pf0 = 0, pf1 = 0;
        if (s0 < s1)     pf0 = (actsrc + (size_t)(pbase + (Ms[s0]&511))*actStride)[lane];
        if (s0 + 1 < s1) pf1 = (actsrc + (size_t)(pbase + (Ms[s0+1]&511))*actStride)[lane];
        for (int s = s0; s < s1; ++s) {
            float f = pf0; pf0 = pf1;
            if (s + 2 < s1) pf1 = (actsrc + (size_t)(pbase + (Ms[s+2]&511))*actStride)[lane];
            unsigned int mt = Ms[s];
            float4 w4 = Ws[s];
            int t0 = (mt>>9)&15, r0 = (mt>>13)&3;
            int r1 = min(r0+1, 2), t1 = (t0+1)&15;
            bool rIsR0 = ((r0 & 1) == rpar);
            bool tIsT0 = ((t0 & 1) == tpar);
            int rsel = rIsR0 ? r0 : r1;
            int tsel = tIsT0 ? t0 : t1;
            float wgt = rIsR0 ? (tIsT0 ? w4.x : w4.y) : (tIsT0 ? w4.z : w4.w);
            int bin = rsel*16 + tsel;
            F1[bin*C8 + lane] += wgt*f;
        }
    }
    __syncthreads();
    float* dst = Fbuf + (size_t)p * Krow;
    const float4* F0v = (const float4*)&Fs[0][0];
    const float4* F1v = (const float4*)&Fs[1][0];
    float4* dv = (float4*)dst;
    for (int i = tid; i < 48*C8/4; i += 512) {
        float4 a = F0v[i], b = F1v[i];
        dv[i] = make_float4(a.x+b.x, a.y+b.y, a.z+b.z, a.w+b.w);
    }
}

// ---------------------------------------------------------------- expand weights into B matrices
__global__ void expand_kernel(const float* __restrict__ Wc, const float* __restrict__ Wd,
                              const float* __restrict__ pc4, const float* __restrict__ pd4,
                              float* __restrict__ Bm, int C, int O8, int total, int mode)
{
    int e = blockIdx.x*blockDim.x + threadIdx.x;
    if (e >= total) return;
    int col = e % O8;
    int k   = e / O8;
    int C8  = C*8;
    bool conv = (k < 48*C8);
    int cc, nn, rr = 0, tt = 0;
    if (conv) {
        int g = k / C8, rem = k - g*C8;
        cc = rem >> 3; nn = rem & 7; rr = g >> 4; tt = g & 15;
    } else {
        int rem = k - 48*C8;
        cc = rem >> 3; nn = rem & 7;
    }
    float val = 0.0f;
    if (mode == 0) {
        int o = col >> 3, m = col & 7;
        if (conv) val = Wc[(((o*C + cc)*8 + ((nn - m) & 7))*3 + rr)*16 + ((tt - 2*m) & 15)];
        else      val = Wd[(o*C + cc)*8 + ((m - nn) & 7)];
    } else if (mode == 1) {
        int o = col >> 3, m = col & 7;
        if (col < 32) { if (conv)  val = Wc[(((o*C + cc)*8 + ((nn - m)&7))*3 + rr)*16 + ((tt - 2*m)&15)]; }
        else          { if (!conv) val = Wd[((o-4)*C + cc)*8 + ((m - nn)&7)]; }
    } else {
        if (col < 6) {
            int co = col >> 1, aa = col & 1;
            float s0 = conv ? pc4[0] : pd4[0];
            float s1 = conv ? pc4[1] : pd4[1];
#pragma unroll
            for (int m = 0; m < 8; ++m) {
                float th = (float)m * 0.7853981633974483f;
                float csv = cosf(th), snv = sinf(th);
                float bas = (aa == 0) ? (s0*csv - s1*snv) : (s0*snv + s1*csv);
                float wv;
                if (conv) wv = Wc[(((co*C + cc)*8 + ((nn - m)&7))*3 + rr)*16 + ((tt - 2*m)&15)];
                else      wv = Wd[(co*C + cc)*8 + ((m - nn)&7)];
                val += wv * bas;
            }
        }
    }
    Bm[e] = val;
}

// ---------------------------------------------------------------- split-K register-tiled f32 GEMM
// C[1024][N] = A[1024][Kdim] * B[Kdim][N]; grid = (16 rowtiles, S splits), KC=224
template<int N>
__global__ __launch_bounds__(256) void gemm_tile(const float* __restrict__ A, int Kdim,
                                                 const float* __restrict__ B,
                                                 float* __restrict__ Cpart)
{
    constexpr int CT = N/16;               // 1, 4, 8
    __shared__ float As[32][68];           // k-major [kk][row], padded
    __shared__ float Bs[32][N];
    int tid = threadIdx.x;
    int tr = tid & 15, tc = tid >> 4;
    int m0 = blockIdx.x * 64;
    int k0base = blockIdx.y * 224;
    float acc[4][CT];
#pragma unroll
    for (int i = 0; i < 4; ++i)
#pragma unroll
        for (int u = 0; u < CT; ++u) acc[i][u] = 0.0f;

    int ar = tid >> 2, aq = (tid & 3) * 8;
    for (int k0 = 0; k0 < 224; k0 += 32) {
        const float* Ap = A + (size_t)(m0 + ar)*Kdim + k0base + k0 + aq;
        float4 av0 = *(const float4*)(Ap);
        float4 av1 = *(const float4*)(Ap + 4);
        As[aq+0][ar] = av0.x; As[aq+1][ar] = av0.y; As[aq+2][ar] = av0.z; As[aq+3][ar] = av0.w;
        As[aq+4][ar] = av1.x; As[aq+5][ar] = av1.y; As[aq+6][ar] = av1.z; As[aq+7][ar] = av1.w;
#pragma unroll
        for (int u = 0; u < (8*N + 255)/256; ++u) {
            int idx = tid + 256*u;
            if (idx < 8*N) {
                int row = idx / (N/4), c4 = idx % (N/4);
                *(float4*)&Bs[row][c4*4] = *(const float4*)(B + (size_t)(k0base + k0 + row)*N + c4*4);
            }
        }
        __syncthreads();
#pragma unroll
        for (int kk = 0; kk < 32; ++kk) {
            float4 a4 = *(const float4*)&As[kk][tr*4];
            if (CT == 1) {
                float bv = Bs[kk][tc];
                acc[0][0] += a4.x*bv; acc[1][0] += a4.y*bv;
                acc[2][0] += a4.z*bv; acc[3][0] += a4.w*bv;
            } else {
#pragma unroll
                for (int uu = 0; uu < CT; uu += 4) {
                    float4 b4 = *(const float4*)&Bs[kk][tc*CT + uu];
                    acc[0][uu+0] += a4.x*b4.x; acc[0][uu+1] += a4.x*b4.y; acc[0][uu+2] += a4.x*b4.z; acc[0][uu+3] += a4.x*b4.w;
                    acc[1][uu+0] += a4.y*b4.x; acc[1][uu+1] += a4.y*b4.y; acc[1][uu+2] += a4.y*b4.z; acc[1][uu+3] += a4.y*b4.w;
                    acc[2][uu+0] += a4.z*b4.x; acc[2][uu+1] += a4.z*b4.y; acc[2][uu+2] += a4.z*b4.z; acc[2][uu+3] += a4.z*b4.w;
                    acc[3][uu+0] += a4.w*b4.x; acc[3][uu+1] += a4.w*b4.y; acc[3][uu+2] += a4.w*b4.z; acc[3][uu+3] += a4.w*b4.w;
                }
            }
        }
        __syncthreads();
    }
    float* Cp = Cpart + ((size_t)blockIdx.y*1024 + m0)*N;
#pragma unroll
    for (int i = 0; i < 4; ++i)
#pragma unroll
        for (int u = 0; u < CT; ++u)
            Cp[(size_t)(tr*4 + i)*N + tc*CT + u] = acc[i][u];
}

// ---------------------------------------------------------------- epilogue: split-reduce + residual + mag_act
__global__ void epilogue_kernel(const float* __restrict__ Cpart, int S, int O, int res,
                                float* __restrict__ outBuf, float* __restrict__ actDst, int actStride)
{
    int id = blockIdx.x*blockDim.x + threadIdx.x;
    if (id >= NPART*O) return;
    int p = id / O, c = id % O;
    int O8 = O*8;
    float x[8];
#pragma unroll
    for (int m = 0; m < 8; ++m) x[m] = 0.0f;
    for (int s = 0; s < S; ++s) {
        const float4* q = (const float4*)(Cpart + ((size_t)(s*1024 + p))*O8 + c*8);
        float4 u0 = q[0], u1 = q[1];
        x[0]+=u0.x; x[1]+=u0.y; x[2]+=u0.z; x[3]+=u0.w;
        x[4]+=u1.x; x[5]+=u1.y; x[6]+=u1.z; x[7]+=u1.w;
    }
    float* ob = outBuf + (size_t)p*O8 + c*8;
    float mag = 1e-6f;
#pragma unroll
    for (int m = 0; m < 8; ++m) {
        float v = x[m];
        if (res) v += ob[m];
        x[m] = v; mag += v*v;
    }
#pragma unroll
    for (int m = 0; m < 8; ++m) ob[m] = x[m];
    float sc = fmaxf(mag - 0.2f, 0.0f) / mag;
    float* ad = actDst + (size_t)p*actStride + c*8;
#pragma unroll
    for (int m = 0; m < 8; ++m) ad[m] = x[m]*sc;
}

// ---------------------------------------------------------------- final outputs (S splits, N=16 partials)
__global__ void final_kernel(const float* __restrict__ Cpart, int S, const float* __restrict__ p1,
                             const float* __restrict__ p0, float* __restrict__ out)
{
    int p = blockIdx.x*blockDim.x + threadIdx.x;
    if (p >= NPART) return;
    float c[6];
#pragma unroll
    for (int t = 0; t < 6; ++t) c[t] = 0.0f;
    for (int s = 0; s < S; ++s) {
        const float* q = Cpart + ((size_t)(s*1024 + p))*16;
#pragma unroll
        for (int t = 0; t < 6; ++t) c[t] += q[t];
    }
    const float sc = 0.0078125f;  // 1/128
#pragma unroll
    for (int t = 0; t < 6; ++t) c[t] *= sc;
    float pcx = p1[p*2+0] + c[0], pcy = p1[p*2+1] + c[1];
    out[p*2+0] = pcx; out[p*2+1] = pcy;
    out[2048 + p*2+0] = pcx - p0[p*2+0];
    out[2048 + p*2+1] = pcy - p0[p*2+1];
    out[4096 + p*4+0] = c[2]; out[4096 + p*4+1] = c[3];
    out[4096 + p*4+2] = c[4]; out[4096 + p*4+3] = c[5];
}

// ---------------------------------------------------------------- launch
extern "C" void kernel_launch(void* const* d_in, const int* in_sizes, int n_in,
                              void* d_out, int out_size, void* d_ws, size_t ws_size,
                              hipStream_t stream)
{
    const float* p0_enc  = (const float*)d_in[0];
    const float* v0_enc  = (const float*)d_in[1];
    const float* p0      = (const float*)d_in[2];
    const float* v0      = (const float*)d_in[3];
    const float* a       = (const float*)d_in[4];
    const float* mask    = (const float*)d_in[5];
    const float* lift_c0 = (const float*)d_in[6];
    const float* Wc0     = (const float*)d_in[7];
    const float* lift_d0 = (const float*)d_in[8];
    const float* Wd0     = (const float*)d_in[9];
    const float* Wc1     = (const float*)d_in[10];
    const float* Wd1     = (const float*)d_in[11];
    const float* Wc2     = (const float*)d_in[12];
    const float* Wd2     = (const float*)d_in[13];
    const float* Wc3     = (const float*)d_in[14];
    const float* Wd3     = (const float*)d_in[15];
    const float* Wc4     = (const float*)d_in[16];
    const float* pc4     = (const float*)d_in[17];
    const float* Wd4     = (const float*)d_in[18];
    const float* pd4     = (const float*)d_in[19];
    float* out = (float*)d_out;

    float* wsf    = (float*)d_ws;
    float* featsC = wsf;                               // 131072
    float* p1     = featsC + 131072;                   // 2048
    float* W4c    = p1 + 2048;                         // 2097152 (float4[1024*512])
    unsigned short* Meta = (unsigned short*)(W4c + 2097152);   // 524288 ushort = 262144 floats
    int*   counts = (int*)(W4c + 2097152 + 262144);    // 1024
    float* Fbuf   = (float*)counts + 1024;             // 6422528
    float* Cpart  = Fbuf + 1024*6272;                  // 1835008 (28*1024*64 = 14*1024*128)
    float* outBuf = Cpart + 1835008;                   // 131072
    float* Bm0    = outBuf + 131072;                   // 6272*64
    float* Bm1    = Bm0 + 6272*64;                     // 3136*64
    float* Bm2    = Bm1 + 3136*64;                     // 3136*128
    float* Bm3    = Bm2 + 3136*128;                    // 6272*64
    float* Bm4    = Bm3 + 6272*64;                     // 3136*16

    prep_kernel<<<NPART, 128, 0, stream>>>(p0_enc, v0_enc, p0, v0, a, lift_c0, lift_d0,
                                           featsC, Fbuf, p1);
    pairs_kernel<<<NPART, 256, 0, stream>>>(p1, mask, (float4*)W4c, Meta, counts);

    {   // expand B matrices
        int t0 = 6272*64;  expand_kernel<<<(t0+255)/256, 256, 0, stream>>>(Wc0, Wd0, pc4, pd4, Bm0, 16,  64, t0, 1);
        int t1 = 3136*64;  expand_kernel<<<(t1+255)/256, 256, 0, stream>>>(Wc1, Wd1, pc4, pd4, Bm1,  8,  64, t1, 0);
        int t2 = 3136*128; expand_kernel<<<(t2+255)/256, 256, 0, stream>>>(Wc2, Wd2, pc4, pd4, Bm2,  8, 128, t2, 0);
        int t3 = 6272*64;  expand_kernel<<<(t3+255)/256, 256, 0, stream>>>(Wc3, Wd3, pc4, pd4, Bm3, 16,  64, t3, 0);
        int t4 = 3136*16;  expand_kernel<<<(t4+255)/256, 256, 0, stream>>>(Wc4, Wd4, pc4, pd4, Bm4,  8,  16, t4, 2);
    }

    // Layer 0  (C8=128, K=6272, S=28)
    aggregate_kernel<128><<<NPART, 512, 0, stream>>>(featsC, 128, (float4*)W4c, Meta, counts, Fbuf, 6272);
    gemm_tile<64><<<dim3(16,28), 256, 0, stream>>>(Fbuf, 6272, Bm0, Cpart);
    epilogue_kernel<<<(NPART*8+63)/64, 64, 0, stream>>>(Cpart, 28, 8, 0, outBuf, Fbuf + 3072, 3136);
    // Layer 1  (C8=64, K=3136, S=14, residual)
    aggregate_kernel<64><<<NPART, 512, 0, stream>>>(Fbuf + 3072, 3136, (float4*)W4c, Meta, counts, Fbuf, 3136);
    gemm_tile<64><<<dim3(16,14), 256, 0, stream>>>(Fbuf, 3136, Bm1, Cpart);
    epilogue_kernel<<<(NPART*8+63)/64, 64, 0, stream>>>(Cpart, 14, 8, 1, outBuf, Fbuf + 3072, 3136);
    // Layer 2  (C8=64 -> O=16, S=14)
    aggregate_kernel<64><<<NPART, 512, 0, stream>>>(Fbuf + 3072, 3136, (float4*)W4c, Meta, counts, Fbuf, 3136);
    gemm_tile<128><<<dim3(16,14), 256, 0, stream>>>(Fbuf, 3136, Bm2, Cpart);
    epilogue_kernel<<<(NPART*16+63)/64, 64, 0, stream>>>(Cpart, 14, 16, 0, outBuf, Fbuf + 6144, 6272);
    // Layer 3  (C8=128 -> O=8, S=28)
    aggregate_kernel<128><<<NPART, 512, 0, stream>>>(Fbuf + 6144, 6272, (float4*)W4c, Meta, counts, Fbuf, 6272);
    gemm_tile<64><<<dim3(16,28), 256, 0, stream>>>(Fbuf, 6272, Bm3, Cpart);
    epilogue_kernel<<<(NPART*8+63)/64, 64, 0, stream>>>(Cpart, 28, 8, 0, outBuf, Fbuf + 3072, 3136);
    // Layer 4  (C8=64 -> N=16 padded, proj folded, S=14)
    aggregate_kernel<64><<<NPART, 512, 0, stream>>>(Fbuf + 3072, 3136, (float4*)W4c, Meta, counts, Fbuf, 3136);
    gemm_tile<16><<<dim3(16,14), 256, 0, stream>>>(Fbuf, 3136, Bm4, Cpart);
    final_kernel<<<4, 256, 0, stream>>>(Cpart, 14, p1, p0, out);
}

// Round 7
// 472.039 us; speedup vs baseline: 3.2518x; 1.1318x over previous
//
#include <hip/hip_runtime.h>

#define NPART 1024
#define NNB   512
#define EMAX  2048   // max sub-entries per particle (4*512)

// ---------------------------------------------------------------- prep
__global__ void prep_kernel(const float* __restrict__ p0_enc, const float* __restrict__ v0_enc,
                            const float* __restrict__ p0, const float* __restrict__ v0,
                            const float* __restrict__ a, const float* __restrict__ liftc,
                            const float* __restrict__ liftd,
                            float* __restrict__ featsC, float* __restrict__ Fbuf,
                            float* __restrict__ p1out)
{
    int p = blockIdx.x;          // b*N + i
    int t = threadIdx.x;         // 128 threads: c*8 + m
    int c = t >> 3, m = t & 7;
    float v0x = v0[p*2+0], v0y = v0[p*2+1];
    float ax  = a[p*2+0],  ay  = a[p*2+1];
    float p0x = p0[p*2+0], p0y = p0[p*2+1];
    float v1x = v0x + ax, v1y = v0y + ay;
    float p1x = p0x + 0.5f*(v0x + v1x), p1y = p0y + 0.5f*(v0y + v1y);
    float vx, vy;
    if (c == 0)      { vx = v1x; vy = v1y; }
    else if (c == 1) { vx = p1x; vy = p1y; }
    else if (c < 9)  { vx = v0_enc[(p*7 + (c-2))*2+0]; vy = v0_enc[(p*7 + (c-2))*2+1]; }
    else             { vx = p0_enc[(p*7 + (c-9))*2+0]; vy = p0_enc[(p*7 + (c-9))*2+1]; }
    float th = (float)m * 0.7853981633974483f;
    float cs = cosf(th), sn = sinf(th);
    float lc0 = liftc[0], lc1 = liftc[1];
    float ld0 = liftd[0], ld1 = liftd[1];
    featsC[p*128 + t]        = vx*(lc0*cs - lc1*sn) + vy*(lc0*sn + lc1*cs);
    Fbuf[p*6272 + 6144 + t]  = vx*(ld0*cs - ld1*sn) + vy*(ld0*sn + ld1*cs);  // layer-0 dense tail
    if (t == 0) { p1out[p*2+0] = p1x; p1out[p*2+1] = p1y; }
}

// ---------------------------------------------------------------- pair weights -> per-bin bucketed lists
// For each particle: up to 4 (bin, weight) sub-entries per neighbor, bucketed by bin g in [0,48).
// Output: Ew[p][slot], Ej[p][slot] sorted by bin; offG[p*64+g] = bin start (49 entries).
__global__ void pairs_kernel(const float* __restrict__ p1, const float* __restrict__ mask,
                             float* __restrict__ Ew, unsigned short* __restrict__ Ej,
                             int* __restrict__ offG)
{
    int p  = blockIdx.x;          // b*N + i
    int b  = p >> 9;
    int ii = p & 511;
    int tid = threadIdx.x;        // 256
    __shared__ float red[256];
    __shared__ float denomS;
    __shared__ int bincnt[48];
    __shared__ int binoff[49];
    __shared__ int binpos[48];
    if (tid < 48) bincnt[tid] = 0;
    float pix = p1[p*2+0], piy = p1[p*2+1];
    float relx[2], rely[2], dd[2], ww[2];
#pragma unroll
    for (int q = 0; q < 2; ++q) {
        int j  = tid + q*256;
        int jr = b*NNB + j;
        float rx = p1[jr*2+0] - pix;
        float ry = p1[jr*2+1] - piy;
        float d  = sqrtf(rx*rx + ry*ry + 1e-12f) * (1.0f/40.0f);
        float t1 = fmaxf(1.0f - d*d, 0.0f);
        float w  = t1*t1*t1 * mask[jr];
        relx[q] = rx; rely[q] = ry; dd[q] = d; ww[q] = w;
    }
    red[tid] = ww[0] + ww[1];
    __syncthreads();
    for (int s = 128; s > 0; s >>= 1) {
        if (tid < s) red[tid] += red[tid+s];
        __syncthreads();
    }
    if (tid == 0) denomS = 1.0f / (red[0] + 1e-6f);
    __syncthreads();
    float dinv = denomS;

    float wsub[2][4];
    int   bsub[2][4];
#pragma unroll
    for (int q = 0; q < 2; ++q) {
        int j  = tid + q*256;
        if (ww[q] == 0.0f) {
#pragma unroll
            for (int k = 0; k < 4; ++k) wsub[q][k] = 0.0f;
            continue;
        }
        float wb = ww[q] * dinv;
        float d  = dd[q];
        float rc  = fminf(fmaxf(d*3.0f - 0.5f, 0.0f), 2.0f);
        float r0f = floorf(rc);
        float wr  = rc - r0f;
        int r0 = (int)r0f;
        int r1 = min(r0 + 1, 2);
        float rx = (j == ii) ? 1.0f : relx[q];
        float ry = (j == ii) ? 0.0f : rely[q];
        float ang = atan2f(ry, rx);
        if (ang < 0.0f) ang += 6.283185307179586f;
        float tc  = ang * 2.546479089470325f;   // *16/(2*pi)
        float t0f = floorf(tc);
        float wt  = tc - t0f;
        int t0  = ((int)t0f) & 15;              // tc==16 edge -> bin 0 like ref's %16
        int t1i = (t0 + 1) & 15;
        wsub[q][0] = wb * (1.0f-wr) * (1.0f-wt);  bsub[q][0] = r0*16 + t0;
        wsub[q][1] = wb * (1.0f-wr) * wt;         bsub[q][1] = r0*16 + t1i;
        wsub[q][2] = wb * wr * (1.0f-wt);         bsub[q][2] = r1*16 + t0;
        wsub[q][3] = wb * wr * wt;                bsub[q][3] = r1*16 + t1i;
#pragma unroll
        for (int k = 0; k < 4; ++k)
            if (wsub[q][k] != 0.0f) atomicAdd(&bincnt[bsub[q][k]], 1);
    }
    __syncthreads();
    if (tid == 0) {
        int s = 0;
#pragma unroll
        for (int g = 0; g < 48; ++g) { binoff[g] = s; s += bincnt[g]; }
        binoff[48] = s;
    }
    __syncthreads();
    if (tid < 48) binpos[tid] = binoff[tid];
    if (tid < 49) offG[p*64 + tid] = binoff[tid];
    __syncthreads();
#pragma unroll
    for (int q = 0; q < 2; ++q) {
        int j = tid + q*256;
#pragma unroll
        for (int k = 0; k < 4; ++k) {
            if (wsub[q][k] != 0.0f) {
                int slot = atomicAdd(&binpos[bsub[q][k]], 1);
                Ew[p*EMAX + slot] = wsub[q][k];
                Ej[p*EMAX + slot] = (unsigned short)j;
            }
        }
    }
}

// ---------------------------------------------------------------- aggregation: streaming register acc per (bin, wave)
// Block = particle, 512 threads = 8 waves; wave wv handles bins g = wv + 8k, k=0..5.
// No LDS, no RMW: acc in registers, one coalesced store per bin.
template<int C8>
__global__ __launch_bounds__(512) void aggregate_kernel(const float* __restrict__ actsrc, int actStride,
                                                        const float* __restrict__ Ew,
                                                        const unsigned short* __restrict__ Ej,
                                                        const int* __restrict__ offG,
                                                        float* __restrict__ Fbuf, int Krow)
{
    int p = blockIdx.x;
    int pbase = p & ~511;            // b*N
    int tid  = threadIdx.x;
    int lane = tid & 63;
    int wv   = tid >> 6;             // 0..7
    const float* ew = Ew + p*EMAX;
    const unsigned short* ej = Ej + p*EMAX;
    const int* off = offG + p*64;
    float* dst = Fbuf + (size_t)p * Krow;

#pragma unroll
    for (int bi = 0; bi < 6; ++bi) {
        int g = wv + bi*8;
        int e0 = off[g], e1 = off[g+1];
        if (C8 == 128) {
            float2 acc = {0.0f, 0.0f};
            float2 f0 = {0,0}, f1 = {0,0};
            float w0 = 0.0f, w1 = 0.0f;
            if (e0 < e1)     { w0 = ew[e0];   f0 = ((const float2*)(actsrc + (size_t)(pbase + ej[e0])*actStride))[lane]; }
            if (e0 + 1 < e1) { w1 = ew[e0+1]; f1 = ((const float2*)(actsrc + (size_t)(pbase + ej[e0+1])*actStride))[lane]; }
            for (int e = e0; e < e1; ++e) {
                float2 f = f0; float w = w0;
                f0 = f1; w0 = w1;
                if (e + 2 < e1) { w1 = ew[e+2]; f1 = ((const float2*)(actsrc + (size_t)(pbase + ej[e+2])*actStride))[lane]; }
                acc.x += w*f.x; acc.y += w*f.y;
            }
            ((float2*)(dst + g*C8))[lane] = acc;
        } else {
            float acc = 0.0f;
            float f0 = 0, f1 = 0, w0 = 0, w1 = 0;
            if (e0 < e1)     { w0 = ew[e0];   f0 = (actsrc + (size_t)(pbase + ej[e0])*actStride)[lane]; }
            if (e0 + 1 < e1) { w1 = ew[e0+1]; f1 = (actsrc + (size_t)(pbase + ej[e0+1])*actStride)[lane]; }
            for (int e = e0; e < e1; ++e) {
                float f = f0; float w = w0;
                f0 = f1; w0 = w1;
                if (e + 2 < e1) { w1 = ew[e+2]; f1 = (actsrc + (size_t)(pbase + ej[e+2])*actStride)[lane]; }
                acc += w*f;
            }
            dst[g*C8 + lane] = acc;
        }
    }
}

// ---------------------------------------------------------------- expand weights into B matrices
__global__ void expand_kernel(const float* __restrict__ Wc, const float* __restrict__ Wd,
                              const float* __restrict__ pc4, const float* __restrict__ pd4,
                              float* __restrict__ Bm, int C, int O8, int total, int mode)
{
    int e = blockIdx.x*blockDim.x + threadIdx.x;
    if (e >= total) return;
    int col = e % O8;
    int k   = e / O8;
    int C8  = C*8;
    bool conv = (k < 48*C8);
    int cc, nn, rr = 0, tt = 0;
    if (conv) {
        int g = k / C8, rem = k - g*C8;
        cc = rem >> 3; nn = rem & 7; rr = g >> 4; tt = g & 15;
    } else {
        int rem = k - 48*C8;
        cc = rem >> 3; nn = rem & 7;
    }
    float val = 0.0f;
    if (mode == 0) {
        int o = col >> 3, m = col & 7;
        if (conv) val = Wc[(((o*C + cc)*8 + ((nn - m) & 7))*3 + rr)*16 + ((tt - 2*m) & 15)];
        else      val = Wd[(o*C + cc)*8 + ((m - nn) & 7)];
    } else if (mode == 1) {
        int o = col >> 3, m = col & 7;
        if (col < 32) { if (conv)  val = Wc[(((o*C + cc)*8 + ((nn - m)&7))*3 + rr)*16 + ((tt - 2*m)&15)]; }
        else          { if (!conv) val = Wd[((o-4)*C + cc)*8 + ((m - nn)&7)]; }
    } else {
        if (col < 6) {
            int co = col >> 1, aa = col & 1;
            float s0 = conv ? pc4[0] : pd4[0];
            float s1 = conv ? pc4[1] : pd4[1];
#pragma unroll
            for (int m = 0; m < 8; ++m) {
                float th = (float)m * 0.7853981633974483f;
                float csv = cosf(th), snv = sinf(th);
                float bas = (aa == 0) ? (s0*csv - s1*snv) : (s0*snv + s1*csv);
                float wv;
                if (conv) wv = Wc[(((co*C + cc)*8 + ((nn - m)&7))*3 + rr)*16 + ((tt - 2*m)&15)];
                else      wv = Wd[(co*C + cc)*8 + ((m - nn)&7)];
                val += wv * bas;
            }
        }
    }
    Bm[e] = val;
}

// ---------------------------------------------------------------- split-K register-tiled f32 GEMM
// C[1024][N] = A[1024][Kdim] * B[Kdim][N]; grid = (16 rowtiles, S splits), KC=224
template<int N>
__global__ __launch_bounds__(256) void gemm_tile(const float* __restrict__ A, int Kdim,
                                                 const float* __restrict__ B,
                                                 float* __restrict__ Cpart)
{
    constexpr int CT = N/16;               // 1, 4, 8
    __shared__ float As[32][68];           // k-major [kk][row], padded
    __shared__ float Bs[32][N];
    int tid = threadIdx.x;
    int tr = tid & 15, tc = tid >> 4;
    int m0 = blockIdx.x * 64;
    int k0base = blockIdx.y * 224;
    float acc[4][CT];
#pragma unroll
    for (int i = 0; i < 4; ++i)
#pragma unroll
        for (int u = 0; u < CT; ++u) acc[i][u] = 0.0f;

    int ar = tid >> 2, aq = (tid & 3) * 8;
    for (int k0 = 0; k0 < 224; k0 += 32) {
        const float* Ap = A + (size_t)(m0 + ar)*Kdim + k0base + k0 + aq;
        float4 av0 = *(const float4*)(Ap);
        float4 av1 = *(const float4*)(Ap + 4);
        As[aq+0][ar] = av0.x; As[aq+1][ar] = av0.y; As[aq+2][ar] = av0.z; As[aq+3][ar] = av0.w;
        As[aq+4][ar] = av1.x; As[aq+5][ar] = av1.y; As[aq+6][ar] = av1.z; As[aq+7][ar] = av1.w;
#pragma unroll
        for (int u = 0; u < (8*N + 255)/256; ++u) {
            int idx = tid + 256*u;
            if (idx < 8*N) {
                int row = idx / (N/4), c4 = idx % (N/4);
                *(float4*)&Bs[row][c4*4] = *(const float4*)(B + (size_t)(k0base + k0 + row)*N + c4*4);
            }
        }
        __syncthreads();
#pragma unroll
        for (int kk = 0; kk < 32; ++kk) {
            float4 a4 = *(const float4*)&As[kk][tr*4];
            if (CT == 1) {
                float bv = Bs[kk][tc];
                acc[0][0] += a4.x*bv; acc[1][0] += a4.y*bv;
                acc[2][0] += a4.z*bv; acc[3][0] += a4.w*bv;
            } else {
#pragma unroll
                for (int uu = 0; uu < CT; uu += 4) {
                    float4 b4 = *(const float4*)&Bs[kk][tc*CT + uu];
                    acc[0][uu+0] += a4.x*b4.x; acc[0][uu+1] += a4.x*b4.y; acc[0][uu+2] += a4.x*b4.z; acc[0][uu+3] += a4.x*b4.w;
                    acc[1][uu+0] += a4.y*b4.x; acc[1][uu+1] += a4.y*b4.y; acc[1][uu+2] += a4.y*b4.z; acc[1][uu+3] += a4.y*b4.w;
                    acc[2][uu+0] += a4.z*b4.x; acc[2][uu+1] += a4.z*b4.y; acc[2][uu+2] += a4.z*b4.z; acc[2][uu+3] += a4.z*b4.w;
                    acc[3][uu+0] += a4.w*b4.x; acc[3][uu+1] += a4.w*b4.y; acc[3][uu+2] += a4.w*b4.z; acc[3][uu+3] += a4.w*b4.w;
                }
            }
        }
        __syncthreads();
    }
    float* Cp = Cpart + ((size_t)blockIdx.y*1024 + m0)*N;
#pragma unroll
    for (int i = 0; i < 4; ++i)
#pragma unroll
        for (int u = 0; u < CT; ++u)
            Cp[(size_t)(tr*4 + i)*N + tc*CT + u] = acc[i][u];
}

// ---------------------------------------------------------------- epilogue: split-reduce + residual + mag_act
__global__ void epilogue_kernel(const float* __restrict__ Cpart, int S, int O, int res,
                                float* __restrict__ outBuf, float* __restrict__ actDst, int actStride)
{
    int id = blockIdx.x*blockDim.x + threadIdx.x;
    if (id >= NPART*O) return;
    int p = id / O, c = id % O;
    int O8 = O*8;
    float x[8];
#pragma unroll
    for (int m = 0; m < 8; ++m) x[m] = 0.0f;
    for (int s = 0; s < S; ++s) {
        const float4* q = (const float4*)(Cpart + ((size_t)(s*1024 + p))*O8 + c*8);
        float4 u0 = q[0], u1 = q[1];
        x[0]+=u0.x; x[1]+=u0.y; x[2]+=u0.z; x[3]+=u0.w;
        x[4]+=u1.x; x[5]+=u1.y; x[6]+=u1.z; x[7]+=u1.w;
    }
    float* ob = outBuf + (size_t)p*O8 + c*8;
    float mag = 1e-6f;
#pragma unroll
    for (int m = 0; m < 8; ++m) {
        float v = x[m];
        if (res) v += ob[m];
        x[m] = v; mag += v*v;
    }
#pragma unroll
    for (int m = 0; m < 8; ++m) ob[m] = x[m];
    float sc = fmaxf(mag - 0.2f, 0.0f) / mag;
    float* ad = actDst + (size_t)p*actStride + c*8;
#pragma unroll
    for (int m = 0; m < 8; ++m) ad[m] = x[m]*sc;
}

// ---------------------------------------------------------------- final outputs (S splits, N=16 partials)
__global__ void final_kernel(const float* __restrict__ Cpart, int S, const float* __restrict__ p1,
                             const float* __restrict__ p0, float* __restrict__ out)
{
    int p = blockIdx.x*blockDim.x + threadIdx.x;
    if (p >= NPART) return;
    float c[6];
#pragma unroll
    for (int t = 0; t < 6; ++t) c[t] = 0.0f;
    for (int s = 0; s < S; ++s) {
        const float* q = Cpart + ((size_t)(s*1024 + p))*16;
#pragma unroll
        for (int t = 0; t < 6; ++t) c[t] += q[t];
    }
    const float sc = 0.0078125f;  // 1/128
#pragma unroll
    for (int t = 0; t < 6; ++t) c[t] *= sc;
    float pcx = p1[p*2+0] + c[0], pcy = p1[p*2+1] + c[1];
    out[p*2+0] = pcx; out[p*2+1] = pcy;
    out[2048 + p*2+0] = pcx - p0[p*2+0];
    out[2048 + p*2+1] = pcy - p0[p*2+1];
    out[4096 + p*4+0] = c[2]; out[4096 + p*4+1] = c[3];
    out[4096 + p*4+2] = c[4]; out[4096 + p*4+3] = c[5];
}

// ---------------------------------------------------------------- launch
extern "C" void kernel_launch(void* const* d_in, const int* in_sizes, int n_in,
                              void* d_out, int out_size, void* d_ws, size_t ws_size,
                              hipStream_t stream)
{
    const float* p0_enc  = (const float*)d_in[0];
    const float* v0_enc  = (const float*)d_in[1];
    const float* p0      = (const float*)d_in[2];
    const float* v0      = (const float*)d_in[3];
    const float* a       = (const float*)d_in[4];
    const float* mask    = (const float*)d_in[5];
    const float* lift_c0 = (const float*)d_in[6];
    const float* Wc0     = (const float*)d_in[7];
    const float* lift_d0 = (const float*)d_in[8];
    const float* Wd0     = (const float*)d_in[9];
    const float* Wc1     = (const float*)d_in[10];
    const float* Wd1     = (const float*)d_in[11];
    const float* Wc2     = (const float*)d_in[12];
    const float* Wd2     = (const float*)d_in[13];
    const float* Wc3     = (const float*)d_in[14];
    const float* Wd3     = (const float*)d_in[15];
    const float* Wc4     = (const float*)d_in[16];
    const float* pc4     = (const float*)d_in[17];
    const float* Wd4     = (const float*)d_in[18];
    const float* pd4     = (const float*)d_in[19];
    float* out = (float*)d_out;

    float* wsf    = (float*)d_ws;
    float* featsC = wsf;                               // 131072
    float* p1     = featsC + 131072;                   // 2048
    float* Ew     = p1 + 2048;                         // 1024*2048 = 2097152
    unsigned short* Ej = (unsigned short*)(Ew + 2097152);  // 2097152 ushort = 1048576 floats
    int*   offG   = (int*)(Ew + 2097152 + 1048576);    // 1024*64 = 65536
    float* Fbuf   = (float*)offG + 65536;              // 6422528
    float* Cpart  = Fbuf + 1024*6272;                  // 1835008 (28*1024*64 = 14*1024*128)
    float* outBuf = Cpart + 1835008;                   // 131072
    float* Bm0    = outBuf + 131072;                   // 6272*64
    float* Bm1    = Bm0 + 6272*64;                     // 3136*64
    float* Bm2    = Bm1 + 3136*64;                     // 3136*128
    float* Bm3    = Bm2 + 3136*128;                    // 6272*64
    float* Bm4    = Bm3 + 6272*64;                     // 3136*16

    prep_kernel<<<NPART, 128, 0, stream>>>(p0_enc, v0_enc, p0, v0, a, lift_c0, lift_d0,
                                           featsC, Fbuf, p1);
    pairs_kernel<<<NPART, 256, 0, stream>>>(p1, mask, Ew, Ej, offG);

    {   // expand B matrices
        int t0 = 6272*64;  expand_kernel<<<(t0+255)/256, 256, 0, stream>>>(Wc0, Wd0, pc4, pd4, Bm0, 16,  64, t0, 1);
        int t1 = 3136*64;  expand_kernel<<<(t1+255)/256, 256, 0, stream>>>(Wc1, Wd1, pc4, pd4, Bm1,  8,  64, t1, 0);
        int t2 = 3136*128; expand_kernel<<<(t2+255)/256, 256, 0, stream>>>(Wc2, Wd2, pc4, pd4, Bm2,  8, 128, t2, 0);
        int t3 = 6272*64;  expand_kernel<<<(t3+255)/256, 256, 0, stream>>>(Wc3, Wd3, pc4, pd4, Bm3, 16,  64, t3, 0);
        int t4 = 3136*16;  expand_kernel<<<(t4+255)/256, 256, 0, stream>>>(Wc4, Wd4, pc4, pd4, Bm4,  8,  16, t4, 2);
    }

    // Layer 0  (C8=128, K=6272, S=28)
    aggregate_kernel<128><<<NPART, 512, 0, stream>>>(featsC, 128, Ew, Ej, offG, Fbuf, 6272);
    gemm_tile<64><<<dim3(16,28), 256, 0, stream>>>(Fbuf, 6272, Bm0, Cpart);
    epilogue_kernel<<<(NPART*8+63)/64, 64, 0, stream>>>(Cpart, 28, 8, 0, outBuf, Fbuf + 3072, 3136);
    // Layer 1  (C8=64, K=3136, S=14, residual)
    aggregate_kernel<64><<<NPART, 512, 0, stream>>>(Fbuf + 3072, 3136, Ew, Ej, offG, Fbuf, 3136);
    gemm_tile<64><<<dim3(16,14), 256, 0, stream>>>(Fbuf, 3136, Bm1, Cpart);
    epilogue_kernel<<<(NPART*8+63)/64, 64, 0, stream>>>(Cpart, 14, 8, 1, outBuf, Fbuf + 3072, 3136);
    // Layer 2  (C8=64 -> O=16, S=14)
    aggregate_kernel<64><<<NPART, 512, 0, stream>>>(Fbuf + 3072, 3136, Ew, Ej, offG, Fbuf, 3136);
    gemm_tile<128><<<dim3(16,14), 256, 0, stream>>>(Fbuf, 3136, Bm2, Cpart);
    epilogue_kernel<<<(NPART*16+63)/64, 64, 0, stream>>>(Cpart, 14, 16, 0, outBuf, Fbuf + 6144, 6272);
    // Layer 3  (C8=128 -> O=8, S=28)
    aggregate_kernel<128><<<NPART, 512, 0, stream>>>(Fbuf + 6144, 6272, Ew, Ej, offG, Fbuf, 6272);
    gemm_tile<64><<<dim3(16,28), 256, 0, stream>>>(Fbuf, 6272, Bm3, Cpart);
    epilogue_kernel<<<(NPART*8+63)/64, 64, 0, stream>>>(Cpart, 28, 8, 0, outBuf, Fbuf + 3072, 3136);
    // Layer 4  (C8=64 -> N=16 padded, proj folded, S=14)
    aggregate_kernel<64><<<NPART, 512, 0, stream>>>(Fbuf + 3072, 3136, Ew, Ej, offG, Fbuf, 3136);
    gemm_tile<16><<<dim3(16,14), 256, 0, stream>>>(Fbuf, 3136, Bm4, Cpart);
    final_kernel<<<4, 256, 0, stream>>>(Cpart, 14, p1, p0, out);
}